// Round 9
// baseline (317.098 us; speedup 1.0000x reference)
//
#include <hip/hip_runtime.h>
#include <math.h>

// Problem constants (shapes fixed by the reference)
#define D 128
#define HH 128
#define CC 64
#define NLAYERS 3
#define LN_EPS 1e-5f

typedef __attribute__((ext_vector_type(8))) short bf16x8;
typedef __attribute__((ext_vector_type(4))) float f32x4;
typedef unsigned short u16;
typedef unsigned int u32;

// round-to-nearest-even fp32 -> bf16 bits
__device__ __forceinline__ u16 f2bf(float f) {
    u32 u = __float_as_uint(f);
    u32 r = u + 0x7FFFu + ((u >> 16) & 1u);
    return (u16)(r >> 16);
}
__device__ __forceinline__ float bf2f(u16 h) {
    return __uint_as_float(((u32)h) << 16);
}

// ---------------------------------------------------------------------------
// k_prep: fused setup — zero cnt + x->bf16 (float4-vectorized, into xcH cols
// 0:128) + tile Wg (3 layers) + tile W1 + tile W2 (hi/lo).
// Tiled layout: [kc][q][n][j], k = kc*32 + q*8 + j.
// ---------------------------------------------------------------------------
__global__ void k_prep(const float* __restrict__ x, u16* __restrict__ xh,
                       const float* __restrict__ Wg, u16* __restrict__ WgtH,
                       const float* __restrict__ W1, u16* __restrict__ W1tH,
                       const float* __restrict__ W2, u16* __restrict__ W2tH,
                       u16* __restrict__ W2tL,
                       int* __restrict__ cnt, int N)
{
    int i = blockIdx.x * blockDim.x + threadIdx.x;
    // seg 0: zero cnt (workspace is poisoned by the harness)
    if (i < N) { cnt[i] = 0; return; }
    i -= N;
    // seg 1: x -> bf16 hi, 4 elements per thread (float4 load, ushort4 store)
    int nx4 = N * (D / 4);
    if (i < nx4) {
        float4 v = *(const float4*)(x + (size_t)i * 4);
        int row = i >> 5, c = (i & 31) << 2;
        ushort4 o;
        o.x = f2bf(v.x); o.y = f2bf(v.y); o.z = f2bf(v.z); o.w = f2bf(v.w);
        *(ushort4*)&xh[(size_t)row * 512 + c] = o;
        return;
    }
    i -= nx4;
    // seg 2: Wg (3 stacked 128x128 matrices; layout linear in kc)
    if (i < NLAYERS * D * HH) {
        int k = i >> 7, n = i & 127;
        int kc = k >> 5, q = (k >> 3) & 3, j = k & 7;
        WgtH[(((kc * 4 + q) << 7) + n) * 8 + j] = f2bf(Wg[i]);
        return;
    }
    i -= NLAYERS * D * HH;
    // seg 3: W1 (512x128)
    if (i < (D + NLAYERS * HH) * HH) {
        int k = i >> 7, n = i & 127;
        int kc = k >> 5, q = (k >> 3) & 3, j = k & 7;
        W1tH[(((kc * 4 + q) << 7) + n) * 8 + j] = f2bf(W1[i]);
        return;
    }
    i -= (D + NLAYERS * HH) * HH;
    // seg 4: W2 (128x64), hi + lo (split-3 in mlp phase 2)
    if (i < HH * CC) {
        int k = i >> 6, n = i & 63;
        int kc = k >> 5, q = (k >> 3) & 3, j = k & 7;
        float v = W2[i];
        u16 h = f2bf(v);
        int o = (((kc * 4 + q) << 6) + n) * 8 + j;
        W2tH[o] = h;
        W2tL[o] = f2bf(v - bf2f(h));
    }
}

// ---------------------------------------------------------------------------
// CSR build: count -> scan_a -> scan_c -> scatter. Separate small launches:
// grid.sync() on MI355X costs ~100 µs/barrier (round-2: fused coop = 527 µs).
// ---------------------------------------------------------------------------

__global__ void k_count(const int* __restrict__ dst, int* __restrict__ cnt, int E) {
    int i = blockIdx.x * blockDim.x + threadIdx.x;
    if (i < E) atomicAdd(&cnt[dst[i]], 1);
}

// shuffle-based block scan: 2 barriers
__global__ void k_scan_a(const int* __restrict__ cnt, int* __restrict__ rowptr,
                         int* __restrict__ bsum, int N) {
    __shared__ int ws[16];
    int tid  = threadIdx.x;              // 1024
    int lane = tid & 63, wv = tid >> 6;  // 16 waves
    int i = blockIdx.x * 1024 + tid;
    int v = (i < N) ? cnt[i] : 0;
    int incl = v;
    #pragma unroll
    for (int off = 1; off < 64; off <<= 1) {
        int u = __shfl_up(incl, off, 64);
        if (lane >= off) incl += u;
    }
    if (lane == 63) ws[wv] = incl;
    __syncthreads();
    if (wv == 0) {
        int s = (lane < 16) ? ws[lane] : 0;
        #pragma unroll
        for (int off = 1; off < 16; off <<= 1) {
            int u = __shfl_up(s, off, 64);
            if (lane >= off) s += u;
        }
        if (lane < 16) ws[lane] = s;    // inclusive over wave sums
    }
    __syncthreads();
    int add = (wv == 0) ? 0 : ws[wv - 1];
    if (i < N) rowptr[i] = add + incl - v;
    if (tid == 1023) bsum[blockIdx.x] = ws[15];
}

// finalize: re-scan <=64 block sums (first wave), apply; compute dinv.
__global__ void k_scan_c(int* __restrict__ rowptr, const int* __restrict__ bsum,
                         const int* __restrict__ cnt, float* __restrict__ dinv,
                         int* __restrict__ cursor, int N, int E, int nsb) {
    __shared__ int sb[64];
    if (threadIdx.x < 64) {
        int t = threadIdx.x;
        int v = (t < nsb) ? bsum[t] : 0;
        int incl = v;
        #pragma unroll
        for (int off = 1; off < 64; off <<= 1) {
            int u = __shfl_up(incl, off, 64);
            if (t >= off) incl += u;
        }
        sb[t] = incl - v;   // exclusive
    }
    __syncthreads();
    int i = blockIdx.x * blockDim.x + threadIdx.x;
    if (i < N) {
        int v = rowptr[i] + sb[i >> 10];
        rowptr[i] = v;
        cursor[i] = v;
        dinv[i] = rsqrtf(1.0f + (float)cnt[i]);
    }
    if (i == 0) rowptr[N] = E;
}

// Scatter edges into CSR; pack src index + precomputed coef (dinv_s * dinv_d)
__global__ void k_scatter(const int* __restrict__ src, const int* __restrict__ dst,
                          const float* __restrict__ dinv,
                          int* __restrict__ cursor, int2* __restrict__ ecol, int E) {
    int i = blockIdx.x * blockDim.x + threadIdx.x;
    if (i < E) {
        int s = src[i], d = dst[i];
        int p = atomicAdd(&cursor[d], 1);
        float c = dinv[s] * dinv[d];
        ecol[p] = make_int2(s, __float_as_int(c));
    }
}

// ---------------------------------------------------------------------------
// Layer GEMM, K=128 (4 chunks): hWb = bf16(A @ W). LDS-free; all fragment
// loads issued up front, then MFMAs. Block 64 rows x 128 cols; wave 32x64.
// ---------------------------------------------------------------------------
__global__ __launch_bounds__(256) void k_gemm_lf(
    const u16* __restrict__ A, int colOff,
    const u16* __restrict__ Bt, u16* __restrict__ OUTb, int N)
{
    const int tid  = threadIdx.x;
    const int lane = tid & 63;
    const int wave = tid >> 6;
    const int wr   = wave & 1;
    const int wc   = wave >> 1;
    const int quad = lane >> 4;
    const int l15  = lane & 15;
    const int row0 = blockIdx.x * 64;

    const u16* pA[2];
    #pragma unroll
    for (int i = 0; i < 2; ++i) {
        int r = row0 + wr * 32 + i * 16 + l15;
        if (r >= N) r = N - 1;
        pA[i] = A + (size_t)r * 512 + colOff + quad * 8;
    }
    const u16* pB = Bt + ((size_t)quad * 128 + wc * 64 + l15) * 8;

    bf16x8 ah[4][2], bh[4][4];
    #pragma unroll
    for (int kc = 0; kc < 4; ++kc) {
        #pragma unroll
        for (int i = 0; i < 2; ++i)
            ah[kc][i] = *(const bf16x8*)(pA[i] + kc * 32);
        #pragma unroll
        for (int j = 0; j < 4; ++j)
            bh[kc][j] = *(const bf16x8*)(pB + (size_t)kc * 4096 + j * 128);
    }

    f32x4 acc[2][4];
    #pragma unroll
    for (int i = 0; i < 2; ++i)
        #pragma unroll
        for (int j = 0; j < 4; ++j)
            #pragma unroll
            for (int r = 0; r < 4; ++r) acc[i][j][r] = 0.f;

    #pragma unroll
    for (int kc = 0; kc < 4; ++kc)
        #pragma unroll
        for (int i = 0; i < 2; ++i)
            #pragma unroll
            for (int j = 0; j < 4; ++j)
                acc[i][j] = __builtin_amdgcn_mfma_f32_16x16x32_bf16(ah[kc][i], bh[kc][j], acc[i][j], 0, 0, 0);

    #pragma unroll
    for (int i = 0; i < 2; ++i)
        #pragma unroll
        for (int j = 0; j < 4; ++j) {
            int col = wc * 64 + j * 16 + l15;
            #pragma unroll
            for (int r = 0; r < 4; ++r) {
                int grow = row0 + wr * 32 + i * 16 + quad * 4 + r;
                if (grow < N)
                    OUTb[(size_t)grow * 128 + col] = f2bf(acc[i][j][r]);
            }
        }
}

// ---------------------------------------------------------------------------
// Fused MLP v4 — sched_barrier-pinned K sub-passes. Rounds 7+8 showed the
// compiler collapses ANY register pipeline (VGPR stayed 36 across both
// variants; loads issued just-in-time; ~450cy exposed per load). v4 shapes
// phase 1 as 4 sub-passes of K=128: {issue 16 loads} -> sched_barrier(0)
// (hard fence, nothing crosses) -> {16 MFMAs}. The vmcnt stall is paid once
// per 16-load batch instead of per load. 4 waves x 32-col quarter, K=512.
// Phase 2 (short): waves 0,1 each 16 rows x 64 cols, split-3 precision.
// ---------------------------------------------------------------------------
__global__ __launch_bounds__(256) void k_mlp_fused(
    const u16* __restrict__ xcH,
    const u16* __restrict__ B1t, const float* __restrict__ b1,
    const u16* __restrict__ W2h, const u16* __restrict__ W2l,
    const float* __restrict__ b2, float* __restrict__ out, int N)
{
    __shared__ u16 sZh[32 * 128];      // [(qq*32 + r)*8 + j], z1 col = qq*8+j
    __shared__ u16 sZl[32 * 128];

    const int tid  = threadIdx.x;
    const int lane = tid & 63;
    const int wave = tid >> 6;   // col quarter: cols wave*32 .. wave*32+31
    const int quad = lane >> 4;
    const int l15  = lane & 15;
    const int row0 = blockIdx.x * 32;

    const u16* pA[2];
    #pragma unroll
    for (int f = 0; f < 2; ++f) {
        int r = row0 + f * 16 + l15;
        if (r >= N) r = N - 1;
        pA[f] = xcH + (size_t)r * 512 + quad * 8;
    }
    const u16* pB = B1t + ((size_t)quad * 128 + wave * 32 + l15) * 8;

    f32x4 acc[2][2];
    #pragma unroll
    for (int f = 0; f < 2; ++f)
        #pragma unroll
        for (int j = 0; j < 2; ++j)
            #pragma unroll
            for (int r = 0; r < 4; ++r) acc[f][j][r] = 0.f;

    // 4 sub-passes of K=128: batch-issue 16 loads, fence, then 16 MFMAs.
    #pragma unroll
    for (int kp = 0; kp < 4; ++kp) {
        bf16x8 ah[4][2], bh[4][2];
        #pragma unroll
        for (int c = 0; c < 4; ++c) {
            const int g = kp * 4 + c;
            #pragma unroll
            for (int f = 0; f < 2; ++f)
                ah[c][f] = *(const bf16x8*)(pA[f] + g * 32);
            #pragma unroll
            for (int j = 0; j < 2; ++j)
                bh[c][j] = *(const bf16x8*)(pB + (size_t)g * 4096 + j * 128);
        }
        __builtin_amdgcn_sched_barrier(0);   // pin: all 16 loads issued first
        #pragma unroll
        for (int c = 0; c < 4; ++c)
            #pragma unroll
            for (int f = 0; f < 2; ++f)
                #pragma unroll
                for (int j = 0; j < 2; ++j)
                    acc[f][j] = __builtin_amdgcn_mfma_f32_16x16x32_bf16(
                        ah[c][f], bh[c][j], acc[f][j], 0, 0, 0);
        __builtin_amdgcn_sched_barrier(0);   // keep next batch after this one
    }

    // bias + relu + hi/lo split -> LDS (each wave writes its 32-col quarter)
    #pragma unroll
    for (int jt = 0; jt < 2; ++jt) {
        int col = wave * 32 + jt * 16 + l15;
        float bv = b1[col];
        int qq = col >> 3, jj = col & 7;
        #pragma unroll
        for (int f = 0; f < 2; ++f) {
            #pragma unroll
            for (int rr = 0; rr < 4; ++rr) {
                int row = f * 16 + quad * 4 + rr;
                float v = fmaxf(acc[f][jt][rr] + bv, 0.f);
                u16 h = f2bf(v);
                sZh[(qq * 32 + row) * 8 + jj] = h;
                sZl[(qq * 32 + row) * 8 + jj] = f2bf(v - bf2f(h));
            }
        }
    }
    __syncthreads();

    // phase 2: MLP2 (128->64) + softmax on waves 0,1 (16 rows each)
    if (wave < 2) {
        f32x4 oacc[4];
        #pragma unroll
        for (int j = 0; j < 4; ++j)
            #pragma unroll
            for (int r = 0; r < 4; ++r) oacc[j][r] = 0.f;

        #pragma unroll
        for (int kc = 0; kc < 4; ++kc) {
            int qq = kc * 4 + quad;
            bf16x8 zh = *(const bf16x8*)&sZh[(qq * 32 + wave * 16 + l15) * 8];
            bf16x8 zl = *(const bf16x8*)&sZl[(qq * 32 + wave * 16 + l15) * 8];
            #pragma unroll
            for (int jt = 0; jt < 4; ++jt) {
                int n = jt * 16 + l15;
                bf16x8 wh = *(const bf16x8*)&W2h[(qq * 64 + n) * 8];
                bf16x8 wl = *(const bf16x8*)&W2l[(qq * 64 + n) * 8];
                oacc[jt] = __builtin_amdgcn_mfma_f32_16x16x32_bf16(zh, wh, oacc[jt], 0, 0, 0);
                oacc[jt] = __builtin_amdgcn_mfma_f32_16x16x32_bf16(zh, wl, oacc[jt], 0, 0, 0);
                oacc[jt] = __builtin_amdgcn_mfma_f32_16x16x32_bf16(zl, wh, oacc[jt], 0, 0, 0);
            }
        }

        #pragma unroll
        for (int jt = 0; jt < 4; ++jt) {
            float bv = b2[jt * 16 + l15];
            #pragma unroll
            for (int r = 0; r < 4; ++r) oacc[jt][r] += bv;
        }
        #pragma unroll
        for (int r = 0; r < 4; ++r) {
            float m = fmaxf(fmaxf(oacc[0][r], oacc[1][r]), fmaxf(oacc[2][r], oacc[3][r]));
            #pragma unroll
            for (int mask = 8; mask; mask >>= 1) m = fmaxf(m, __shfl_xor(m, mask, 64));
            float p0 = __expf(oacc[0][r] - m);
            float p1 = __expf(oacc[1][r] - m);
            float p2 = __expf(oacc[2][r] - m);
            float p3 = __expf(oacc[3][r] - m);
            float s = p0 + p1 + p2 + p3;
            #pragma unroll
            for (int mask = 8; mask; mask >>= 1) s += __shfl_xor(s, mask, 64);
            float inv = 1.0f / s;
            int grow = row0 + wave * 16 + quad * 4 + r;
            if (grow < N) {
                float* o = out + (size_t)grow * CC + l15;
                o[0]  = p0 * inv;
                o[16] = p1 * inv;
                o[32] = p2 * inv;
                o[48] = p3 * inv;
            }
        }
    }
}

// ---------------------------------------------------------------------------
// Aggregation (symmetric-normalized, self-loop) + bias + LayerNorm + ReLU.
// Node-per-half-wave: each 32-lane half owns a DIFFERENT node (4 cols/lane,
// 8B gathers). One edge stream per node -> batch-4 runs ~deg/4 = 3 full
// iterations (4 independent gathers in flight), tiny tail. Two nodes per
// wave = 2x independent latency chains. (Verified round 6: agg left top-5.)
// ---------------------------------------------------------------------------
__global__ __launch_bounds__(256, 8) void k_agg_ln(
    const u16* __restrict__ hWb,
    const int* __restrict__ rowptr, const int2* __restrict__ ecol,
    const float* __restrict__ dinv,
    const float* __restrict__ bg, const float* __restrict__ g,
    const float* __restrict__ b,
    u16* __restrict__ outHi, int N)
{
    const int lane = threadIdx.x & 63;
    const int c0   = (lane & 31) << 2;  // 4 owned columns (within half)

    const float4 bgv = *(const float4*)(bg + c0);
    const float4 gv  = *(const float4*)(g + c0);
    const float4 bv  = *(const float4*)(b + c0);

    const int nslots = gridDim.x * 8;   // 2 nodes per wave, 4 waves per block
    for (int wid = blockIdx.x * 8 + ((threadIdx.x >> 6) << 1) + (lane >> 5);
         wid < N; wid += nslots) {
        float di = dinv[wid];
        float sc = di * di;

        // self-loop term
        uint2 hv = *(const uint2*)(hWb + (size_t)wid * HH + c0);
        float a0 = bf2f((u16)hv.x) * sc;
        float a1 = bf2f((u16)(hv.x >> 16)) * sc;
        float a2 = bf2f((u16)hv.y) * sc;
        float a3 = bf2f((u16)(hv.y >> 16)) * sc;
        float q0 = 0.f, q1 = 0.f, q2 = 0.f, q3 = 0.f;

        int e0 = rowptr[wid];
        int m  = rowptr[wid + 1] - e0;
        const int2* ep = ecol + e0;

        int k = 0;
        for (; k + 4 <= m; k += 4) {     // 4 independent gathers in flight
            int2 p[4];
            uint2 v[4];
            #pragma unroll
            for (int t = 0; t < 4; ++t) p[t] = ep[k + t];
            #pragma unroll
            for (int t = 0; t < 4; ++t)
                v[t] = *(const uint2*)(hWb + (size_t)p[t].x * HH + c0);
            #pragma unroll
            for (int t = 0; t < 4; ++t) {
                float c = __int_as_float(p[t].y);
                float x0 = bf2f((u16)v[t].x) * c;
                float x1 = bf2f((u16)(v[t].x >> 16)) * c;
                float x2 = bf2f((u16)v[t].y) * c;
                float x3 = bf2f((u16)(v[t].y >> 16)) * c;
                if (t & 1) { q0 += x0; q1 += x1; q2 += x2; q3 += x3; }
                else       { a0 += x0; a1 += x1; a2 += x2; a3 += x3; }
            }
        }
        if (k < m) {                     // tail <=3, issue together
            int2 p0 = ep[k];
            int2 p1 = (k + 1 < m) ? ep[k + 1] : p0;
            int2 p2 = (k + 2 < m) ? ep[k + 2] : p0;
            uint2 v0 = *(const uint2*)(hWb + (size_t)p0.x * HH + c0);
            uint2 v1 = *(const uint2*)(hWb + (size_t)p1.x * HH + c0);
            uint2 v2 = *(const uint2*)(hWb + (size_t)p2.x * HH + c0);
            float cc0 = __int_as_float(p0.y);
            float cc1 = (k + 1 < m) ? __int_as_float(p1.y) : 0.f;
            float cc2 = (k + 2 < m) ? __int_as_float(p2.y) : 0.f;
            a0 += bf2f((u16)v0.x) * cc0;  a1 += bf2f((u16)(v0.x >> 16)) * cc0;
            a2 += bf2f((u16)v0.y) * cc0;  a3 += bf2f((u16)(v0.y >> 16)) * cc0;
            q0 += bf2f((u16)v1.x) * cc1;  q1 += bf2f((u16)(v1.x >> 16)) * cc1;
            q2 += bf2f((u16)v1.y) * cc1;  q3 += bf2f((u16)(v1.y >> 16)) * cc1;
            a0 += bf2f((u16)v2.x) * cc2;  a1 += bf2f((u16)(v2.x >> 16)) * cc2;
            a2 += bf2f((u16)v2.y) * cc2;  a3 += bf2f((u16)(v2.y >> 16)) * cc2;
        }
        a0 += q0; a1 += q1; a2 += q2; a3 += q3;
        a0 += bgv.x; a1 += bgv.y; a2 += bgv.z; a3 += bgv.w;

        // LayerNorm over 128 cols (reduce within the 32-lane half)
        float ssum = (a0 + a1) + (a2 + a3);
        #pragma unroll
        for (int off = 16; off; off >>= 1) ssum += __shfl_xor(ssum, off, 64);
        float mu = ssum * (1.0f / 128.0f);
        float d0 = a0 - mu, d1 = a1 - mu, d2 = a2 - mu, d3 = a3 - mu;
        float vsum = (d0 * d0 + d1 * d1) + (d2 * d2 + d3 * d3);
        #pragma unroll
        for (int off = 16; off; off >>= 1) vsum += __shfl_xor(vsum, off, 64);
        float rstd = rsqrtf(vsum * (1.0f / 128.0f) + LN_EPS);

        float o0 = fmaxf(gv.x * d0 * rstd + bv.x, 0.f);
        float o1 = fmaxf(gv.y * d1 * rstd + bv.y, 0.f);
        float o2 = fmaxf(gv.z * d2 * rstd + bv.z, 0.f);
        float o3 = fmaxf(gv.w * d3 * rstd + bv.w, 0.f);
        uint2 o;
        o.x = (u32)f2bf(o0) | ((u32)f2bf(o1) << 16);
        o.y = (u32)f2bf(o2) | ((u32)f2bf(o3) << 16);
        *(uint2*)&outHi[(size_t)wid * 512 + c0] = o;
    }
}

// ---------------------------------------------------------------------------
// Host launcher
// ---------------------------------------------------------------------------
extern "C" void kernel_launch(void* const* d_in, const int* in_sizes, int n_in,
                              void* d_out, int out_size, void* d_ws, size_t ws_size,
                              hipStream_t stream) {
    const float* x   = (const float*)d_in[0];
    const int*   ei  = (const int*)  d_in[1];
    const float* Wg  = (const float*)d_in[2];
    const float* bg  = (const float*)d_in[3];
    const float* lng = (const float*)d_in[4];
    const float* lnb = (const float*)d_in[5];
    const float* W1  = (const float*)d_in[6];
    const float* b1  = (const float*)d_in[7];
    const float* W2  = (const float*)d_in[8];
    const float* b2  = (const float*)d_in[9];
    float* out = (float*)d_out;

    const int N = in_sizes[0] / D;
    const int E = in_sizes[1] / 2;
    const int* srcp = ei;
    const int* dstp = ei + E;

    char* ws = (char*)d_ws;
    size_t off = 0;
    auto alloc = [&](size_t bytes) -> void* {
        void* p = ws + off;
        off += (bytes + 511) & ~(size_t)511;
        return p;
    };
    int*   cnt    = (int*)  alloc((size_t)N * 4);
    int*   rowptr = (int*)  alloc((size_t)(N + 1) * 4);
    int*   cursor = (int*)  alloc((size_t)N * 4);
    int*   bsum   = (int*)  alloc(64 * 4);
    int2*  ecol   = (int2*) alloc((size_t)E * 8);
    float* dinv   = (float*)alloc((size_t)N * 4);
    u16*   hWb    = (u16*)  alloc((size_t)N * HH * 2);       // layer GEMM bf16 out
    u16*   xcH    = (u16*)  alloc((size_t)N * 512 * 2);      // [x|f1|f2|f3] bf16
    u16*   WgtH   = (u16*)  alloc((size_t)NLAYERS * D * HH * 2);
    u16*   W1tH   = (u16*)  alloc((size_t)(D + NLAYERS * HH) * HH * 2);
    u16*   W2tH   = (u16*)  alloc((size_t)HH * CC * 2);
    u16*   W2tL   = (u16*)  alloc((size_t)HH * CC * 2);

    const int B = 256;
    const int gE = (E + B - 1) / B;
    const int nsb = (N + 1023) / 1024;

    // fused prep: zero cnt + x->bf16 (x4) + all weight tilings (one launch)
    const int prepTotal = N + N * (D / 4) + NLAYERS * D * HH
                        + (D + NLAYERS * HH) * HH + HH * CC;
    k_prep<<<(prepTotal + B - 1) / B, B, 0, stream>>>(x, xcH, Wg, WgtH, W1, W1tH,
                                                      W2, W2tH, W2tL, cnt, N);
    k_count<<<gE, B, 0, stream>>>(dstp, cnt, E);
    k_scan_a<<<nsb, 1024, 0, stream>>>(cnt, rowptr, bsum, N);
    k_scan_c<<<(N + B - 1) / B, B, 0, stream>>>(rowptr, bsum, cnt, dinv, cursor, N, E, nsb);
    k_scatter<<<gE, B, 0, stream>>>(srcp, dstp, dinv, cursor, ecol, E);

    const int gemmBlocks = (N + 63) / 64;
    const int mlpBlocks  = (N + 31) / 32;
    const int aggBlocks  = 2048;   // persistent: 8192 waves x 2 nodes

    for (int l = 0; l < NLAYERS; ++l) {
        // hWb = bf16(h @ Wg[l])  (bias added after aggregation)
        k_gemm_lf<<<gemmBlocks, B, 0, stream>>>(xcH, l * HH,
                                                WgtH + (size_t)l * D * HH, hWb, N);
        k_agg_ln<<<aggBlocks, B, 0, stream>>>(hWb, rowptr, ecol, dinv,
                                              bg + (size_t)l * HH,
                                              lng + (size_t)l * HH,
                                              lnb + (size_t)l * HH,
                                              xcH + (size_t)(l + 1) * HH, N);
    }

    // out = softmax(relu([x|f1|f2|f3] @ W1 + b1) @ W2 + b2), fused, no K-split
    k_mlp_fused<<<mlpBlocks, B, 0, stream>>>(xcH, W1tH, b1,
                                             W2tH, W2tL, b2, out, N);
}

// Round 10
// 311.700 us; speedup vs baseline: 1.0173x; 1.0173x over previous
//
#include <hip/hip_runtime.h>
#include <math.h>

// Problem constants (shapes fixed by the reference)
#define D 128
#define HH 128
#define CC 64
#define NLAYERS 3
#define LN_EPS 1e-5f

typedef __attribute__((ext_vector_type(8))) short bf16x8;
typedef __attribute__((ext_vector_type(4))) float f32x4;
typedef unsigned short u16;
typedef unsigned int u32;

// round-to-nearest-even fp32 -> bf16 bits
__device__ __forceinline__ u16 f2bf(float f) {
    u32 u = __float_as_uint(f);
    u32 r = u + 0x7FFFu + ((u >> 16) & 1u);
    return (u16)(r >> 16);
}
__device__ __forceinline__ float bf2f(u16 h) {
    return __uint_as_float(((u32)h) << 16);
}

// ---------------------------------------------------------------------------
// k_prep: fused setup — x->bf16 (float4) + tile Wg/W1/W2 + EDGE COUNTING
// (fused from the old k_count; cnt is zeroed by hipMemsetAsync before this
// launch, so the atomicAdd segment is ordering-safe). Count atomics overlap
// the streaming weight-tile stores.
// Tiled layout: [kc][q][n][j], k = kc*32 + q*8 + j.
// ---------------------------------------------------------------------------
__global__ void k_prep(const float* __restrict__ x, u16* __restrict__ xh,
                       const float* __restrict__ Wg, u16* __restrict__ WgtH,
                       const float* __restrict__ W1, u16* __restrict__ W1tH,
                       const float* __restrict__ W2, u16* __restrict__ W2tH,
                       u16* __restrict__ W2tL,
                       const int* __restrict__ dst, int* __restrict__ cnt,
                       int N, int E)
{
    int i = blockIdx.x * blockDim.x + threadIdx.x;
    // seg 0: x -> bf16 hi, 4 elements per thread (float4 load, ushort4 store)
    int nx4 = N * (D / 4);
    if (i < nx4) {
        float4 v = *(const float4*)(x + (size_t)i * 4);
        int row = i >> 5, c = (i & 31) << 2;
        ushort4 o;
        o.x = f2bf(v.x); o.y = f2bf(v.y); o.z = f2bf(v.z); o.w = f2bf(v.w);
        *(ushort4*)&xh[(size_t)row * 512 + c] = o;
        return;
    }
    i -= nx4;
    // seg 1: Wg (3 stacked 128x128 matrices; layout linear in kc)
    if (i < NLAYERS * D * HH) {
        int k = i >> 7, n = i & 127;
        int kc = k >> 5, q = (k >> 3) & 3, j = k & 7;
        WgtH[(((kc * 4 + q) << 7) + n) * 8 + j] = f2bf(Wg[i]);
        return;
    }
    i -= NLAYERS * D * HH;
    // seg 2: W1 (512x128)
    if (i < (D + NLAYERS * HH) * HH) {
        int k = i >> 7, n = i & 127;
        int kc = k >> 5, q = (k >> 3) & 3, j = k & 7;
        W1tH[(((kc * 4 + q) << 7) + n) * 8 + j] = f2bf(W1[i]);
        return;
    }
    i -= (D + NLAYERS * HH) * HH;
    // seg 3: W2 (128x64), hi + lo (split-3 in mlp phase 2)
    if (i < HH * CC) {
        int k = i >> 6, n = i & 63;
        int kc = k >> 5, q = (k >> 3) & 3, j = k & 7;
        float v = W2[i];
        u16 h = f2bf(v);
        int o = (((kc * 4 + q) << 6) + n) * 8 + j;
        W2tH[o] = h;
        W2tL[o] = f2bf(v - bf2f(h));
        return;
    }
    i -= HH * CC;
    // seg 4: edge degree count (cnt pre-zeroed by hipMemsetAsync)
    if (i < E) atomicAdd(&cnt[dst[i]], 1);
}

// ---------------------------------------------------------------------------
// CSR build: scan_a -> scan_c -> scatter. Separate small launches:
// grid.sync() on MI355X costs ~100 µs/barrier (round-2: fused coop = 527 µs).
// ---------------------------------------------------------------------------

// shuffle-based block scan: 2 barriers
__global__ void k_scan_a(const int* __restrict__ cnt, int* __restrict__ rowptr,
                         int* __restrict__ bsum, int N) {
    __shared__ int ws[16];
    int tid  = threadIdx.x;              // 1024
    int lane = tid & 63, wv = tid >> 6;  // 16 waves
    int i = blockIdx.x * 1024 + tid;
    int v = (i < N) ? cnt[i] : 0;
    int incl = v;
    #pragma unroll
    for (int off = 1; off < 64; off <<= 1) {
        int u = __shfl_up(incl, off, 64);
        if (lane >= off) incl += u;
    }
    if (lane == 63) ws[wv] = incl;
    __syncthreads();
    if (wv == 0) {
        int s = (lane < 16) ? ws[lane] : 0;
        #pragma unroll
        for (int off = 1; off < 16; off <<= 1) {
            int u = __shfl_up(s, off, 64);
            if (lane >= off) s += u;
        }
        if (lane < 16) ws[lane] = s;    // inclusive over wave sums
    }
    __syncthreads();
    int add = (wv == 0) ? 0 : ws[wv - 1];
    if (i < N) rowptr[i] = add + incl - v;
    if (tid == 1023) bsum[blockIdx.x] = ws[15];
}

// finalize: re-scan <=64 block sums (first wave), apply; compute dinv.
__global__ void k_scan_c(int* __restrict__ rowptr, const int* __restrict__ bsum,
                         const int* __restrict__ cnt, float* __restrict__ dinv,
                         int* __restrict__ cursor, int N, int E, int nsb) {
    __shared__ int sb[64];
    if (threadIdx.x < 64) {
        int t = threadIdx.x;
        int v = (t < nsb) ? bsum[t] : 0;
        int incl = v;
        #pragma unroll
        for (int off = 1; off < 64; off <<= 1) {
            int u = __shfl_up(incl, off, 64);
            if (t >= off) incl += u;
        }
        sb[t] = incl - v;   // exclusive
    }
    __syncthreads();
    int i = blockIdx.x * blockDim.x + threadIdx.x;
    if (i < N) {
        int v = rowptr[i] + sb[i >> 10];
        rowptr[i] = v;
        cursor[i] = v;
        dinv[i] = rsqrtf(1.0f + (float)cnt[i]);
    }
    if (i == 0) rowptr[N] = E;
}

// Scatter edges into CSR; pack src index + precomputed coef (dinv_s * dinv_d)
__global__ void k_scatter(const int* __restrict__ src, const int* __restrict__ dst,
                          const float* __restrict__ dinv,
                          int* __restrict__ cursor, int2* __restrict__ ecol, int E) {
    int i = blockIdx.x * blockDim.x + threadIdx.x;
    if (i < E) {
        int s = src[i], d = dst[i];
        int p = atomicAdd(&cursor[d], 1);
        float c = dinv[s] * dinv[d];
        ecol[p] = make_int2(s, __float_as_int(c));
    }
}

// ---------------------------------------------------------------------------
// Layer GEMM, K=128 (4 chunks): hWb = bf16(A @ W). LDS-free; all fragment
// loads issued up front, then MFMAs. Block 64 rows x 128 cols; wave 32x64.
// ---------------------------------------------------------------------------
__global__ __launch_bounds__(256) void k_gemm_lf(
    const u16* __restrict__ A, int colOff,
    const u16* __restrict__ Bt, u16* __restrict__ OUTb, int N)
{
    const int tid  = threadIdx.x;
    const int lane = tid & 63;
    const int wave = tid >> 6;
    const int wr   = wave & 1;
    const int wc   = wave >> 1;
    const int quad = lane >> 4;
    const int l15  = lane & 15;
    const int row0 = blockIdx.x * 64;

    const u16* pA[2];
    #pragma unroll
    for (int i = 0; i < 2; ++i) {
        int r = row0 + wr * 32 + i * 16 + l15;
        if (r >= N) r = N - 1;
        pA[i] = A + (size_t)r * 512 + colOff + quad * 8;
    }
    const u16* pB = Bt + ((size_t)quad * 128 + wc * 64 + l15) * 8;

    bf16x8 ah[4][2], bh[4][4];
    #pragma unroll
    for (int kc = 0; kc < 4; ++kc) {
        #pragma unroll
        for (int i = 0; i < 2; ++i)
            ah[kc][i] = *(const bf16x8*)(pA[i] + kc * 32);
        #pragma unroll
        for (int j = 0; j < 4; ++j)
            bh[kc][j] = *(const bf16x8*)(pB + (size_t)kc * 4096 + j * 128);
    }

    f32x4 acc[2][4];
    #pragma unroll
    for (int i = 0; i < 2; ++i)
        #pragma unroll
        for (int j = 0; j < 4; ++j)
            #pragma unroll
            for (int r = 0; r < 4; ++r) acc[i][j][r] = 0.f;

    #pragma unroll
    for (int kc = 0; kc < 4; ++kc)
        #pragma unroll
        for (int i = 0; i < 2; ++i)
            #pragma unroll
            for (int j = 0; j < 4; ++j)
                acc[i][j] = __builtin_amdgcn_mfma_f32_16x16x32_bf16(ah[kc][i], bh[kc][j], acc[i][j], 0, 0, 0);

    #pragma unroll
    for (int i = 0; i < 2; ++i)
        #pragma unroll
        for (int j = 0; j < 4; ++j) {
            int col = wc * 64 + j * 16 + l15;
            #pragma unroll
            for (int r = 0; r < 4; ++r) {
                int grow = row0 + wr * 32 + i * 16 + quad * 4 + r;
                if (grow < N)
                    OUTb[(size_t)grow * 128 + col] = f2bf(acc[i][j][r]);
            }
        }
}

// ---------------------------------------------------------------------------
// Fused MLP v5 — full k_gemm_lf block shape: 64 rows x 128 cols, 4 waves
// (wave tile 32x64), K=512 as 4 sequential K=128 passes with all fragments
// loaded up front per pass. Rounds 7-9: three register-pipeline variants all
// 42.5 µs at 920 GB/s -> scheduling was not the lever; per-block W1 re-read
// amortization is (each 32-row block re-read 128 KB of W1 from L2). 64 rows
// halves that; phase 2 now uses ALL 4 waves (16 rows each).
// ---------------------------------------------------------------------------
__global__ __launch_bounds__(256) void k_mlp_fused(
    const u16* __restrict__ xcH,
    const u16* __restrict__ B1t, const float* __restrict__ b1,
    const u16* __restrict__ W2h, const u16* __restrict__ W2l,
    const float* __restrict__ b2, float* __restrict__ out, int N)
{
    __shared__ u16 sZh[64 * 128];      // [(qq*64 + row)*8 + jj], z1 col = qq*8+jj
    __shared__ u16 sZl[64 * 128];      // 32 KB total

    const int tid  = threadIdx.x;
    const int lane = tid & 63;
    const int wave = tid >> 6;
    const int wr   = wave & 1;   // row half (32 rows)
    const int wc   = wave >> 1;  // col half (64 cols)
    const int quad = lane >> 4;
    const int l15  = lane & 15;
    const int row0 = blockIdx.x * 64;

    const u16* pA[2];
    #pragma unroll
    for (int i = 0; i < 2; ++i) {
        int r = row0 + wr * 32 + i * 16 + l15;
        if (r >= N) r = N - 1;
        pA[i] = xcH + (size_t)r * 512 + quad * 8;
    }
    const u16* pB = B1t + ((size_t)quad * 128 + wc * 64 + l15) * 8;

    f32x4 acc[2][4];
    #pragma unroll
    for (int i = 0; i < 2; ++i)
        #pragma unroll
        for (int j = 0; j < 4; ++j)
            #pragma unroll
            for (int r = 0; r < 4; ++r) acc[i][j][r] = 0.f;

    // 4 sequential K=128 passes, gemm_lf-style (24 loads up front, 32 MFMAs)
    #pragma unroll
    for (int kp = 0; kp < 4; ++kp) {
        bf16x8 ah[4][2], bh[4][4];
        #pragma unroll
        for (int c = 0; c < 4; ++c) {
            const int g = kp * 4 + c;
            #pragma unroll
            for (int i = 0; i < 2; ++i)
                ah[c][i] = *(const bf16x8*)(pA[i] + g * 32);
            #pragma unroll
            for (int j = 0; j < 4; ++j)
                bh[c][j] = *(const bf16x8*)(pB + (size_t)g * 4096 + j * 128);
        }
        #pragma unroll
        for (int c = 0; c < 4; ++c)
            #pragma unroll
            for (int i = 0; i < 2; ++i)
                #pragma unroll
                for (int j = 0; j < 4; ++j)
                    acc[i][j] = __builtin_amdgcn_mfma_f32_16x16x32_bf16(
                        ah[c][i], bh[c][j], acc[i][j], 0, 0, 0);
    }

    // bias + relu + hi/lo split -> LDS (each wave writes its 32x64 tile)
    #pragma unroll
    for (int jt = 0; jt < 4; ++jt) {
        int col = wc * 64 + jt * 16 + l15;
        float bv = b1[col];
        int qq = col >> 3, jj = col & 7;
        #pragma unroll
        for (int i = 0; i < 2; ++i) {
            #pragma unroll
            for (int rr = 0; rr < 4; ++rr) {
                int row = wr * 32 + i * 16 + quad * 4 + rr;
                float v = fmaxf(acc[i][jt][rr] + bv, 0.f);
                u16 h = f2bf(v);
                sZh[(qq * 64 + row) * 8 + jj] = h;
                sZl[(qq * 64 + row) * 8 + jj] = f2bf(v - bf2f(h));
            }
        }
    }
    __syncthreads();

    // phase 2: MLP2 (128->64) + softmax; ALL 4 waves, 16 rows each
    {
        f32x4 oacc[4];
        #pragma unroll
        for (int j = 0; j < 4; ++j)
            #pragma unroll
            for (int r = 0; r < 4; ++r) oacc[j][r] = 0.f;

        #pragma unroll
        for (int kc = 0; kc < 4; ++kc) {
            int qq = kc * 4 + quad;
            bf16x8 zh = *(const bf16x8*)&sZh[(qq * 64 + wave * 16 + l15) * 8];
            bf16x8 zl = *(const bf16x8*)&sZl[(qq * 64 + wave * 16 + l15) * 8];
            #pragma unroll
            for (int jt = 0; jt < 4; ++jt) {
                int n = jt * 16 + l15;
                bf16x8 wh = *(const bf16x8*)&W2h[(qq * 64 + n) * 8];
                bf16x8 wl = *(const bf16x8*)&W2l[(qq * 64 + n) * 8];
                oacc[jt] = __builtin_amdgcn_mfma_f32_16x16x32_bf16(zh, wh, oacc[jt], 0, 0, 0);
                oacc[jt] = __builtin_amdgcn_mfma_f32_16x16x32_bf16(zh, wl, oacc[jt], 0, 0, 0);
                oacc[jt] = __builtin_amdgcn_mfma_f32_16x16x32_bf16(zl, wh, oacc[jt], 0, 0, 0);
            }
        }

        #pragma unroll
        for (int jt = 0; jt < 4; ++jt) {
            float bv = b2[jt * 16 + l15];
            #pragma unroll
            for (int r = 0; r < 4; ++r) oacc[jt][r] += bv;
        }
        #pragma unroll
        for (int r = 0; r < 4; ++r) {
            float m = fmaxf(fmaxf(oacc[0][r], oacc[1][r]), fmaxf(oacc[2][r], oacc[3][r]));
            #pragma unroll
            for (int mask = 8; mask; mask >>= 1) m = fmaxf(m, __shfl_xor(m, mask, 64));
            float p0 = __expf(oacc[0][r] - m);
            float p1 = __expf(oacc[1][r] - m);
            float p2 = __expf(oacc[2][r] - m);
            float p3 = __expf(oacc[3][r] - m);
            float s = p0 + p1 + p2 + p3;
            #pragma unroll
            for (int mask = 8; mask; mask >>= 1) s += __shfl_xor(s, mask, 64);
            float inv = 1.0f / s;
            int grow = row0 + wave * 16 + quad * 4 + r;
            if (grow < N) {
                float* o = out + (size_t)grow * CC + l15;
                o[0]  = p0 * inv;
                o[16] = p1 * inv;
                o[32] = p2 * inv;
                o[48] = p3 * inv;
            }
        }
    }
}

// ---------------------------------------------------------------------------
// Aggregation (symmetric-normalized, self-loop) + bias + LayerNorm + ReLU.
// Node-per-half-wave (verified round 6: left top-5). 4 cols/lane, 8B gathers,
// batch-4 (4 independent gathers in flight), 2 nodes/wave.
// ---------------------------------------------------------------------------
__global__ __launch_bounds__(256, 8) void k_agg_ln(
    const u16* __restrict__ hWb,
    const int* __restrict__ rowptr, const int2* __restrict__ ecol,
    const float* __restrict__ dinv,
    const float* __restrict__ bg, const float* __restrict__ g,
    const float* __restrict__ b,
    u16* __restrict__ outHi, int N)
{
    const int lane = threadIdx.x & 63;
    const int c0   = (lane & 31) << 2;  // 4 owned columns (within half)

    const float4 bgv = *(const float4*)(bg + c0);
    const float4 gv  = *(const float4*)(g + c0);
    const float4 bv  = *(const float4*)(b + c0);

    const int nslots = gridDim.x * 8;   // 2 nodes per wave, 4 waves per block
    for (int wid = blockIdx.x * 8 + ((threadIdx.x >> 6) << 1) + (lane >> 5);
         wid < N; wid += nslots) {
        float di = dinv[wid];
        float sc = di * di;

        // self-loop term
        uint2 hv = *(const uint2*)(hWb + (size_t)wid * HH + c0);
        float a0 = bf2f((u16)hv.x) * sc;
        float a1 = bf2f((u16)(hv.x >> 16)) * sc;
        float a2 = bf2f((u16)hv.y) * sc;
        float a3 = bf2f((u16)(hv.y >> 16)) * sc;
        float q0 = 0.f, q1 = 0.f, q2 = 0.f, q3 = 0.f;

        int e0 = rowptr[wid];
        int m  = rowptr[wid + 1] - e0;
        const int2* ep = ecol + e0;

        int k = 0;
        for (; k + 4 <= m; k += 4) {     // 4 independent gathers in flight
            int2 p[4];
            uint2 v[4];
            #pragma unroll
            for (int t = 0; t < 4; ++t) p[t] = ep[k + t];
            #pragma unroll
            for (int t = 0; t < 4; ++t)
                v[t] = *(const uint2*)(hWb + (size_t)p[t].x * HH + c0);
            #pragma unroll
            for (int t = 0; t < 4; ++t) {
                float c = __int_as_float(p[t].y);
                float x0 = bf2f((u16)v[t].x) * c;
                float x1 = bf2f((u16)(v[t].x >> 16)) * c;
                float x2 = bf2f((u16)v[t].y) * c;
                float x3 = bf2f((u16)(v[t].y >> 16)) * c;
                if (t & 1) { q0 += x0; q1 += x1; q2 += x2; q3 += x3; }
                else       { a0 += x0; a1 += x1; a2 += x2; a3 += x3; }
            }
        }
        if (k < m) {                     // tail <=3, issue together
            int2 p0 = ep[k];
            int2 p1 = (k + 1 < m) ? ep[k + 1] : p0;
            int2 p2 = (k + 2 < m) ? ep[k + 2] : p0;
            uint2 v0 = *(const uint2*)(hWb + (size_t)p0.x * HH + c0);
            uint2 v1 = *(const uint2*)(hWb + (size_t)p1.x * HH + c0);
            uint2 v2 = *(const uint2*)(hWb + (size_t)p2.x * HH + c0);
            float cc0 = __int_as_float(p0.y);
            float cc1 = (k + 1 < m) ? __int_as_float(p1.y) : 0.f;
            float cc2 = (k + 2 < m) ? __int_as_float(p2.y) : 0.f;
            a0 += bf2f((u16)v0.x) * cc0;  a1 += bf2f((u16)(v0.x >> 16)) * cc0;
            a2 += bf2f((u16)v0.y) * cc0;  a3 += bf2f((u16)(v0.y >> 16)) * cc0;
            q0 += bf2f((u16)v1.x) * cc1;  q1 += bf2f((u16)(v1.x >> 16)) * cc1;
            q2 += bf2f((u16)v1.y) * cc1;  q3 += bf2f((u16)(v1.y >> 16)) * cc1;
            a0 += bf2f((u16)v2.x) * cc2;  a1 += bf2f((u16)(v2.x >> 16)) * cc2;
            a2 += bf2f((u16)v2.y) * cc2;  a3 += bf2f((u16)(v2.y >> 16)) * cc2;
        }
        a0 += q0; a1 += q1; a2 += q2; a3 += q3;
        a0 += bgv.x; a1 += bgv.y; a2 += bgv.z; a3 += bgv.w;

        // LayerNorm over 128 cols (reduce within the 32-lane half)
        float ssum = (a0 + a1) + (a2 + a3);
        #pragma unroll
        for (int off = 16; off; off >>= 1) ssum += __shfl_xor(ssum, off, 64);
        float mu = ssum * (1.0f / 128.0f);
        float d0 = a0 - mu, d1 = a1 - mu, d2 = a2 - mu, d3 = a3 - mu;
        float vsum = (d0 * d0 + d1 * d1) + (d2 * d2 + d3 * d3);
        #pragma unroll
        for (int off = 16; off; off >>= 1) vsum += __shfl_xor(vsum, off, 64);
        float rstd = rsqrtf(vsum * (1.0f / 128.0f) + LN_EPS);

        float o0 = fmaxf(gv.x * d0 * rstd + bv.x, 0.f);
        float o1 = fmaxf(gv.y * d1 * rstd + bv.y, 0.f);
        float o2 = fmaxf(gv.z * d2 * rstd + bv.z, 0.f);
        float o3 = fmaxf(gv.w * d3 * rstd + bv.w, 0.f);
        uint2 o;
        o.x = (u32)f2bf(o0) | ((u32)f2bf(o1) << 16);
        o.y = (u32)f2bf(o2) | ((u32)f2bf(o3) << 16);
        *(uint2*)&outHi[(size_t)wid * 512 + c0] = o;
    }
}

// ---------------------------------------------------------------------------
// Host launcher
// ---------------------------------------------------------------------------
extern "C" void kernel_launch(void* const* d_in, const int* in_sizes, int n_in,
                              void* d_out, int out_size, void* d_ws, size_t ws_size,
                              hipStream_t stream) {
    const float* x   = (const float*)d_in[0];
    const int*   ei  = (const int*)  d_in[1];
    const float* Wg  = (const float*)d_in[2];
    const float* bg  = (const float*)d_in[3];
    const float* lng = (const float*)d_in[4];
    const float* lnb = (const float*)d_in[5];
    const float* W1  = (const float*)d_in[6];
    const float* b1  = (const float*)d_in[7];
    const float* W2  = (const float*)d_in[8];
    const float* b2  = (const float*)d_in[9];
    float* out = (float*)d_out;

    const int N = in_sizes[0] / D;
    const int E = in_sizes[1] / 2;
    const int* srcp = ei;
    const int* dstp = ei + E;

    char* ws = (char*)d_ws;
    size_t off = 0;
    auto alloc = [&](size_t bytes) -> void* {
        void* p = ws + off;
        off += (bytes + 511) & ~(size_t)511;
        return p;
    };
    int*   cnt    = (int*)  alloc((size_t)N * 4);
    int*   rowptr = (int*)  alloc((size_t)(N + 1) * 4);
    int*   cursor = (int*)  alloc((size_t)N * 4);
    int*   bsum   = (int*)  alloc(64 * 4);
    int2*  ecol   = (int2*) alloc((size_t)E * 8);
    float* dinv   = (float*)alloc((size_t)N * 4);
    u16*   hWb    = (u16*)  alloc((size_t)N * HH * 2);       // layer GEMM bf16 out
    u16*   xcH    = (u16*)  alloc((size_t)N * 512 * 2);      // [x|f1|f2|f3] bf16
    u16*   WgtH   = (u16*)  alloc((size_t)NLAYERS * D * HH * 2);
    u16*   W1tH   = (u16*)  alloc((size_t)(D + NLAYERS * HH) * HH * 2);
    u16*   W2tH   = (u16*)  alloc((size_t)HH * CC * 2);
    u16*   W2tL   = (u16*)  alloc((size_t)HH * CC * 2);

    const int B = 256;
    const int gE = (E + B - 1) / B;
    const int nsb = (N + 1023) / 1024;

    // zero degree counts (stream-ordered; graph-capture legal)
    hipMemsetAsync(cnt, 0, (size_t)N * 4, stream);

    // fused prep: x->bf16 (x4) + all weight tilings + edge counting
    const int prepTotal = N * (D / 4) + NLAYERS * D * HH
                        + (D + NLAYERS * HH) * HH + HH * CC + E;
    k_prep<<<(prepTotal + B - 1) / B, B, 0, stream>>>(x, xcH, Wg, WgtH, W1, W1tH,
                                                      W2, W2tH, W2tL, dstp, cnt, N, E);
    k_scan_a<<<nsb, 1024, 0, stream>>>(cnt, rowptr, bsum, N);
    k_scan_c<<<(N + B - 1) / B, B, 0, stream>>>(rowptr, bsum, cnt, dinv, cursor, N, E, nsb);
    k_scatter<<<gE, B, 0, stream>>>(srcp, dstp, dinv, cursor, ecol, E);

    const int gemmBlocks = (N + 63) / 64;
    const int mlpBlocks  = (N + 63) / 64;
    const int aggBlocks  = 2048;   // persistent: 8192 waves x 2 nodes

    for (int l = 0; l < NLAYERS; ++l) {
        // hWb = bf16(h @ Wg[l])  (bias added after aggregation)
        k_gemm_lf<<<gemmBlocks, B, 0, stream>>>(xcH, l * HH,
                                                WgtH + (size_t)l * D * HH, hWb, N);
        k_agg_ln<<<aggBlocks, B, 0, stream>>>(hWb, rowptr, ecol, dinv,
                                              bg + (size_t)l * HH,
                                              lng + (size_t)l * HH,
                                              lnb + (size_t)l * HH,
                                              xcH + (size_t)(l + 1) * HH, N);
    }

    // out = softmax(relu([x|f1|f2|f3] @ W1 + b1) @ W2 + b2), fused
    k_mlp_fused<<<mlpBlocks, B, 0, stream>>>(xcH, W1tH, b1,
                                             W2tH, W2tL, b2, out, N);
}

// Round 11
// 294.022 us; speedup vs baseline: 1.0785x; 1.0601x over previous
//
#include <hip/hip_runtime.h>
#include <math.h>

// Problem constants (shapes fixed by the reference)
#define D 128
#define HH 128
#define CC 64
#define NLAYERS 3
#define LN_EPS 1e-5f

typedef __attribute__((ext_vector_type(8))) short bf16x8;
typedef __attribute__((ext_vector_type(4))) float f32x4;
typedef unsigned short u16;
typedef unsigned int u32;

// round-to-nearest-even fp32 -> bf16 bits
__device__ __forceinline__ u16 f2bf(float f) {
    u32 u = __float_as_uint(f);
    u32 r = u + 0x7FFFu + ((u >> 16) & 1u);
    return (u16)(r >> 16);
}
__device__ __forceinline__ float bf2f(u16 h) {
    return __uint_as_float(((u32)h) << 16);
}

// async global->LDS DMA, 16 B per lane (dest = wave-uniform base + lane*16)
__device__ __forceinline__ void gload_lds16(const void* g, void* l) {
    __builtin_amdgcn_global_load_lds(
        (const __attribute__((address_space(1))) void*)g,
        (__attribute__((address_space(3))) void*)l, 16, 0, 0);
}

// ---------------------------------------------------------------------------
// k_prep: fused setup — x->bf16 (float4) + tile Wg/W1/W2 + edge counting
// (cnt zeroed by hipMemsetAsync before this launch).
// Tiled layout: [kc][q][n][j], k = kc*32 + q*8 + j.
// ---------------------------------------------------------------------------
__global__ void k_prep(const float* __restrict__ x, u16* __restrict__ xh,
                       const float* __restrict__ Wg, u16* __restrict__ WgtH,
                       const float* __restrict__ W1, u16* __restrict__ W1tH,
                       const float* __restrict__ W2, u16* __restrict__ W2tH,
                       u16* __restrict__ W2tL,
                       const int* __restrict__ dst, int* __restrict__ cnt,
                       int N, int E)
{
    int i = blockIdx.x * blockDim.x + threadIdx.x;
    // seg 0: x -> bf16 hi, 4 elements per thread (float4 load, ushort4 store)
    int nx4 = N * (D / 4);
    if (i < nx4) {
        float4 v = *(const float4*)(x + (size_t)i * 4);
        int row = i >> 5, c = (i & 31) << 2;
        ushort4 o;
        o.x = f2bf(v.x); o.y = f2bf(v.y); o.z = f2bf(v.z); o.w = f2bf(v.w);
        *(ushort4*)&xh[(size_t)row * 512 + c] = o;
        return;
    }
    i -= nx4;
    // seg 1: Wg (3 stacked 128x128 matrices; layout linear in kc)
    if (i < NLAYERS * D * HH) {
        int k = i >> 7, n = i & 127;
        int kc = k >> 5, q = (k >> 3) & 3, j = k & 7;
        WgtH[(((kc * 4 + q) << 7) + n) * 8 + j] = f2bf(Wg[i]);
        return;
    }
    i -= NLAYERS * D * HH;
    // seg 2: W1 (512x128)
    if (i < (D + NLAYERS * HH) * HH) {
        int k = i >> 7, n = i & 127;
        int kc = k >> 5, q = (k >> 3) & 3, j = k & 7;
        W1tH[(((kc * 4 + q) << 7) + n) * 8 + j] = f2bf(W1[i]);
        return;
    }
    i -= (D + NLAYERS * HH) * HH;
    // seg 3: W2 (128x64), hi + lo (split-3 in mlp phase 2)
    if (i < HH * CC) {
        int k = i >> 6, n = i & 63;
        int kc = k >> 5, q = (k >> 3) & 3, j = k & 7;
        float v = W2[i];
        u16 h = f2bf(v);
        int o = (((kc * 4 + q) << 6) + n) * 8 + j;
        W2tH[o] = h;
        W2tL[o] = f2bf(v - bf2f(h));
        return;
    }
    i -= HH * CC;
    // seg 4: edge degree count (cnt pre-zeroed by hipMemsetAsync)
    if (i < E) atomicAdd(&cnt[dst[i]], 1);
}

// ---------------------------------------------------------------------------
// CSR build: scan_a -> scan_c -> scatter. Separate small launches:
// grid.sync() on MI355X costs ~100 µs/barrier (round-2: fused coop = 527 µs).
// ---------------------------------------------------------------------------

// shuffle-based block scan: 2 barriers
__global__ void k_scan_a(const int* __restrict__ cnt, int* __restrict__ rowptr,
                         int* __restrict__ bsum, int N) {
    __shared__ int ws[16];
    int tid  = threadIdx.x;              // 1024
    int lane = tid & 63, wv = tid >> 6;  // 16 waves
    int i = blockIdx.x * 1024 + tid;
    int v = (i < N) ? cnt[i] : 0;
    int incl = v;
    #pragma unroll
    for (int off = 1; off < 64; off <<= 1) {
        int u = __shfl_up(incl, off, 64);
        if (lane >= off) incl += u;
    }
    if (lane == 63) ws[wv] = incl;
    __syncthreads();
    if (wv == 0) {
        int s = (lane < 16) ? ws[lane] : 0;
        #pragma unroll
        for (int off = 1; off < 16; off <<= 1) {
            int u = __shfl_up(s, off, 64);
            if (lane >= off) s += u;
        }
        if (lane < 16) ws[lane] = s;    // inclusive over wave sums
    }
    __syncthreads();
    int add = (wv == 0) ? 0 : ws[wv - 1];
    if (i < N) rowptr[i] = add + incl - v;
    if (tid == 1023) bsum[blockIdx.x] = ws[15];
}

// finalize: re-scan <=64 block sums (first wave), apply; compute dinv.
__global__ void k_scan_c(int* __restrict__ rowptr, const int* __restrict__ bsum,
                         const int* __restrict__ cnt, float* __restrict__ dinv,
                         int* __restrict__ cursor, int N, int E, int nsb) {
    __shared__ int sb[64];
    if (threadIdx.x < 64) {
        int t = threadIdx.x;
        int v = (t < nsb) ? bsum[t] : 0;
        int incl = v;
        #pragma unroll
        for (int off = 1; off < 64; off <<= 1) {
            int u = __shfl_up(incl, off, 64);
            if (t >= off) incl += u;
        }
        sb[t] = incl - v;   // exclusive
    }
    __syncthreads();
    int i = blockIdx.x * blockDim.x + threadIdx.x;
    if (i < N) {
        int v = rowptr[i] + sb[i >> 10];
        rowptr[i] = v;
        cursor[i] = v;
        dinv[i] = rsqrtf(1.0f + (float)cnt[i]);
    }
    if (i == 0) rowptr[N] = E;
}

// Scatter edges into CSR; pack src index + precomputed coef (dinv_s * dinv_d)
__global__ void k_scatter(const int* __restrict__ src, const int* __restrict__ dst,
                          const float* __restrict__ dinv,
                          int* __restrict__ cursor, int2* __restrict__ ecol, int E) {
    int i = blockIdx.x * blockDim.x + threadIdx.x;
    if (i < E) {
        int s = src[i], d = dst[i];
        int p = atomicAdd(&cursor[d], 1);
        float c = dinv[s] * dinv[d];
        ecol[p] = make_int2(s, __float_as_int(c));
    }
}

// ---------------------------------------------------------------------------
// Layer GEMM v2, K=128: A-tile (64x128, 16 KB) staged via global_load_lds DMA
// (coalesced 1KB/instruction, no VGPR destinations to serialize on — rounds
// 7-10 proved the compiler collapses any register-resident load pipeline and
// the direct A-reads were 16x64B scattered). XOR-granule swizzle on the
// GLOBAL source (LDS dest linear per HW rule) + same XOR on ds_read -> 2-way
// bank aliasing (free). B direct from L2 (broadcast-hot, 256B segments).
// Block 64 rows x 128 cols; wave tile 32x64.
// ---------------------------------------------------------------------------
__global__ __launch_bounds__(256) void k_gemm_lf(
    const u16* __restrict__ A, int colOff,
    const u16* __restrict__ Bt, u16* __restrict__ OUTb, int N)
{
    __shared__ u16 sA[64 * 128];   // 16 KB, [row][granule^ (row&7)] of 8 u16

    const int tid  = threadIdx.x;
    const int lane = tid & 63;
    const int wave = tid >> 6;
    const int wr   = wave & 1;
    const int wc   = wave >> 1;
    const int quad = lane >> 4;
    const int l15  = lane & 15;
    const int row0 = blockIdx.x * 64;

    // stage A tile: 4 rounds x 256 lanes x 16 B = 16 KB
    #pragma unroll
    for (int rd = 0; rd < 4; ++rd) {
        int idx  = rd * 256 + tid;           // slot 0..1023
        int row  = idx >> 4;                 // 0..63
        int gp   = idx & 15;                 // LDS granule
        int gs   = gp ^ (row & 7);           // swizzled source granule
        int grow = row0 + row; if (grow >= N) grow = N - 1;
        const u16* src = A + (size_t)grow * 512 + colOff + gs * 8;
        gload_lds16(src, &sA[(size_t)(rd * 256 + (tid & ~63)) * 8]);
    }

    const u16* pB = Bt + ((size_t)quad * 128 + wc * 64 + l15) * 8;
    bf16x8 bh[4][4];
    #pragma unroll
    for (int kc = 0; kc < 4; ++kc)
        #pragma unroll
        for (int j = 0; j < 4; ++j)
            bh[kc][j] = *(const bf16x8*)(pB + (size_t)kc * 4096 + j * 128);

    __syncthreads();   // drains vmcnt (incl. global_load_lds)

    const int rL[2] = { wr * 32 + l15, wr * 32 + 16 + l15 };
    bf16x8 ah[4][2];
    #pragma unroll
    for (int kc = 0; kc < 4; ++kc)
        #pragma unroll
        for (int i = 0; i < 2; ++i)
            ah[kc][i] = *(const bf16x8*)&sA[rL[i] * 128
                           + (((kc << 2) | quad) ^ (rL[i] & 7)) * 8];

    f32x4 acc[2][4];
    #pragma unroll
    for (int i = 0; i < 2; ++i)
        #pragma unroll
        for (int j = 0; j < 4; ++j)
            #pragma unroll
            for (int r = 0; r < 4; ++r) acc[i][j][r] = 0.f;

    #pragma unroll
    for (int kc = 0; kc < 4; ++kc)
        #pragma unroll
        for (int i = 0; i < 2; ++i)
            #pragma unroll
            for (int j = 0; j < 4; ++j)
                acc[i][j] = __builtin_amdgcn_mfma_f32_16x16x32_bf16(ah[kc][i], bh[kc][j], acc[i][j], 0, 0, 0);

    #pragma unroll
    for (int i = 0; i < 2; ++i)
        #pragma unroll
        for (int j = 0; j < 4; ++j) {
            int col = wc * 64 + j * 16 + l15;
            #pragma unroll
            for (int r = 0; r < 4; ++r) {
                int grow = row0 + wr * 32 + i * 16 + quad * 4 + r;
                if (grow < N)
                    OUTb[(size_t)grow * 128 + col] = f2bf(acc[i][j][r]);
            }
        }
}

// ---------------------------------------------------------------------------
// Fused MLP v6 — A staged via global_load_lds per K=128 pass (same mechanism
// as k_gemm_lf v2; the 900 GB/s wall was invariant across 4 register-pipeline
// variants -> attack the load mechanism itself). 64 rows x 128 cols, 4 waves,
// K=512 = 4 single-buffered passes {stage 16KB -> barrier -> compute ->
// barrier}. Phase 2 on all 4 waves. LDS: sA 16K + sZh/sZl 32K = 48 KB.
// ---------------------------------------------------------------------------
__global__ __launch_bounds__(256) void k_mlp_fused(
    const u16* __restrict__ xcH,
    const u16* __restrict__ B1t, const float* __restrict__ b1,
    const u16* __restrict__ W2h, const u16* __restrict__ W2l,
    const float* __restrict__ b2, float* __restrict__ out, int N)
{
    __shared__ u16 sA[64 * 128];       // 16 KB staged A (granule-swizzled)
    __shared__ u16 sZh[64 * 128];      // [(qq*64 + row)*8 + jj]
    __shared__ u16 sZl[64 * 128];

    const int tid  = threadIdx.x;
    const int lane = tid & 63;
    const int wave = tid >> 6;
    const int wr   = wave & 1;   // row half (32 rows)
    const int wc   = wave >> 1;  // col half (64 cols)
    const int quad = lane >> 4;
    const int l15  = lane & 15;
    const int row0 = blockIdx.x * 64;

    const u16* pB = B1t + ((size_t)quad * 128 + wc * 64 + l15) * 8;
    const int rL[2] = { wr * 32 + l15, wr * 32 + 16 + l15 };

    f32x4 acc[2][4];
    #pragma unroll
    for (int i = 0; i < 2; ++i)
        #pragma unroll
        for (int j = 0; j < 4; ++j)
            #pragma unroll
            for (int r = 0; r < 4; ++r) acc[i][j][r] = 0.f;

    #pragma unroll
    for (int kp = 0; kp < 4; ++kp) {
        // stage A rows [row0, row0+64) x K cols [kp*128, kp*128+128)
        #pragma unroll
        for (int rd = 0; rd < 4; ++rd) {
            int idx  = rd * 256 + tid;
            int row  = idx >> 4;
            int gp   = idx & 15;
            int gs   = gp ^ (row & 7);
            int grow = row0 + row; if (grow >= N) grow = N - 1;
            const u16* src = xcH + (size_t)grow * 512 + kp * 128 + gs * 8;
            gload_lds16(src, &sA[(size_t)(rd * 256 + (tid & ~63)) * 8]);
        }
        // B fragments for this K pass (direct; L2-broadcast-hot)
        bf16x8 bh[4][4];
        #pragma unroll
        for (int c = 0; c < 4; ++c)
            #pragma unroll
            for (int j = 0; j < 4; ++j)
                bh[c][j] = *(const bf16x8*)(pB + (size_t)(kp * 4 + c) * 4096 + j * 128);

        __syncthreads();   // A staged (vmcnt drained)

        bf16x8 ah[4][2];
        #pragma unroll
        for (int c = 0; c < 4; ++c)
            #pragma unroll
            for (int i = 0; i < 2; ++i)
                ah[c][i] = *(const bf16x8*)&sA[rL[i] * 128
                               + (((c << 2) | quad) ^ (rL[i] & 7)) * 8];

        #pragma unroll
        for (int c = 0; c < 4; ++c)
            #pragma unroll
            for (int i = 0; i < 2; ++i)
                #pragma unroll
                for (int j = 0; j < 4; ++j)
                    acc[i][j] = __builtin_amdgcn_mfma_f32_16x16x32_bf16(
                        ah[c][i], bh[c][j], acc[i][j], 0, 0, 0);

        __syncthreads();   // all reads of sA done before next stage
    }

    // bias + relu + hi/lo split -> LDS (each wave writes its 32x64 tile)
    #pragma unroll
    for (int jt = 0; jt < 4; ++jt) {
        int col = wc * 64 + jt * 16 + l15;
        float bv = b1[col];
        int qq = col >> 3, jj = col & 7;
        #pragma unroll
        for (int i = 0; i < 2; ++i) {
            #pragma unroll
            for (int rr = 0; rr < 4; ++rr) {
                int row = wr * 32 + i * 16 + quad * 4 + rr;
                float v = fmaxf(acc[i][jt][rr] + bv, 0.f);
                u16 h = f2bf(v);
                sZh[(qq * 64 + row) * 8 + jj] = h;
                sZl[(qq * 64 + row) * 8 + jj] = f2bf(v - bf2f(h));
            }
        }
    }
    __syncthreads();

    // phase 2: MLP2 (128->64) + softmax; ALL 4 waves, 16 rows each
    {
        f32x4 oacc[4];
        #pragma unroll
        for (int j = 0; j < 4; ++j)
            #pragma unroll
            for (int r = 0; r < 4; ++r) oacc[j][r] = 0.f;

        #pragma unroll
        for (int kc = 0; kc < 4; ++kc) {
            int qq = kc * 4 + quad;
            bf16x8 zh = *(const bf16x8*)&sZh[(qq * 64 + wave * 16 + l15) * 8];
            bf16x8 zl = *(const bf16x8*)&sZl[(qq * 64 + wave * 16 + l15) * 8];
            #pragma unroll
            for (int jt = 0; jt < 4; ++jt) {
                int n = jt * 16 + l15;
                bf16x8 wh = *(const bf16x8*)&W2h[(qq * 64 + n) * 8];
                bf16x8 wl = *(const bf16x8*)&W2l[(qq * 64 + n) * 8];
                oacc[jt] = __builtin_amdgcn_mfma_f32_16x16x32_bf16(zh, wh, oacc[jt], 0, 0, 0);
                oacc[jt] = __builtin_amdgcn_mfma_f32_16x16x32_bf16(zh, wl, oacc[jt], 0, 0, 0);
                oacc[jt] = __builtin_amdgcn_mfma_f32_16x16x32_bf16(zl, wh, oacc[jt], 0, 0, 0);
            }
        }

        #pragma unroll
        for (int jt = 0; jt < 4; ++jt) {
            float bv = b2[jt * 16 + l15];
            #pragma unroll
            for (int r = 0; r < 4; ++r) oacc[jt][r] += bv;
        }
        #pragma unroll
        for (int r = 0; r < 4; ++r) {
            float m = fmaxf(fmaxf(oacc[0][r], oacc[1][r]), fmaxf(oacc[2][r], oacc[3][r]));
            #pragma unroll
            for (int mask = 8; mask; mask >>= 1) m = fmaxf(m, __shfl_xor(m, mask, 64));
            float p0 = __expf(oacc[0][r] - m);
            float p1 = __expf(oacc[1][r] - m);
            float p2 = __expf(oacc[2][r] - m);
            float p3 = __expf(oacc[3][r] - m);
            float s = p0 + p1 + p2 + p3;
            #pragma unroll
            for (int mask = 8; mask; mask >>= 1) s += __shfl_xor(s, mask, 64);
            float inv = 1.0f / s;
            int grow = row0 + wave * 16 + quad * 4 + r;
            if (grow < N) {
                float* o = out + (size_t)grow * CC + l15;
                o[0]  = p0 * inv;
                o[16] = p1 * inv;
                o[32] = p2 * inv;
                o[48] = p3 * inv;
            }
        }
    }
}

// ---------------------------------------------------------------------------
// Aggregation (symmetric-normalized, self-loop) + bias + LayerNorm + ReLU.
// Node-per-half-wave (verified round 6). 4 cols/lane, 8B gathers, batch-4,
// 2 nodes/wave. Achieves ~3 TB/s effective — unchanged.
// ---------------------------------------------------------------------------
__global__ __launch_bounds__(256, 8) void k_agg_ln(
    const u16* __restrict__ hWb,
    const int* __restrict__ rowptr, const int2* __restrict__ ecol,
    const float* __restrict__ dinv,
    const float* __restrict__ bg, const float* __restrict__ g,
    const float* __restrict__ b,
    u16* __restrict__ outHi, int N)
{
    const int lane = threadIdx.x & 63;
    const int c0   = (lane & 31) << 2;  // 4 owned columns (within half)

    const float4 bgv = *(const float4*)(bg + c0);
    const float4 gv  = *(const float4*)(g + c0);
    const float4 bv  = *(const float4*)(b + c0);

    const int nslots = gridDim.x * 8;   // 2 nodes per wave, 4 waves per block
    for (int wid = blockIdx.x * 8 + ((threadIdx.x >> 6) << 1) + (lane >> 5);
         wid < N; wid += nslots) {
        float di = dinv[wid];
        float sc = di * di;

        // self-loop term
        uint2 hv = *(const uint2*)(hWb + (size_t)wid * HH + c0);
        float a0 = bf2f((u16)hv.x) * sc;
        float a1 = bf2f((u16)(hv.x >> 16)) * sc;
        float a2 = bf2f((u16)hv.y) * sc;
        float a3 = bf2f((u16)(hv.y >> 16)) * sc;
        float q0 = 0.f, q1 = 0.f, q2 = 0.f, q3 = 0.f;

        int e0 = rowptr[wid];
        int m  = rowptr[wid + 1] - e0;
        const int2* ep = ecol + e0;

        int k = 0;
        for (; k + 4 <= m; k += 4) {     // 4 independent gathers in flight
            int2 p[4];
            uint2 v[4];
            #pragma unroll
            for (int t = 0; t < 4; ++t) p[t] = ep[k + t];
            #pragma unroll
            for (int t = 0; t < 4; ++t)
                v[t] = *(const uint2*)(hWb + (size_t)p[t].x * HH + c0);
            #pragma unroll
            for (int t = 0; t < 4; ++t) {
                float c = __int_as_float(p[t].y);
                float x0 = bf2f((u16)v[t].x) * c;
                float x1 = bf2f((u16)(v[t].x >> 16)) * c;
                float x2 = bf2f((u16)v[t].y) * c;
                float x3 = bf2f((u16)(v[t].y >> 16)) * c;
                if (t & 1) { q0 += x0; q1 += x1; q2 += x2; q3 += x3; }
                else       { a0 += x0; a1 += x1; a2 += x2; a3 += x3; }
            }
        }
        if (k < m) {                     // tail <=3, issue together
            int2 p0 = ep[k];
            int2 p1 = (k + 1 < m) ? ep[k + 1] : p0;
            int2 p2 = (k + 2 < m) ? ep[k + 2] : p0;
            uint2 v0 = *(const uint2*)(hWb + (size_t)p0.x * HH + c0);
            uint2 v1 = *(const uint2*)(hWb + (size_t)p1.x * HH + c0);
            uint2 v2 = *(const uint2*)(hWb + (size_t)p2.x * HH + c0);
            float cc0 = __int_as_float(p0.y);
            float cc1 = (k + 1 < m) ? __int_as_float(p1.y) : 0.f;
            float cc2 = (k + 2 < m) ? __int_as_float(p2.y) : 0.f;
            a0 += bf2f((u16)v0.x) * cc0;  a1 += bf2f((u16)(v0.x >> 16)) * cc0;
            a2 += bf2f((u16)v0.y) * cc0;  a3 += bf2f((u16)(v0.y >> 16)) * cc0;
            q0 += bf2f((u16)v1.x) * cc1;  q1 += bf2f((u16)(v1.x >> 16)) * cc1;
            q2 += bf2f((u16)v1.y) * cc1;  q3 += bf2f((u16)(v1.y >> 16)) * cc1;
            a0 += bf2f((u16)v2.x) * cc2;  a1 += bf2f((u16)(v2.x >> 16)) * cc2;
            a2 += bf2f((u16)v2.y) * cc2;  a3 += bf2f((u16)(v2.y >> 16)) * cc2;
        }
        a0 += q0; a1 += q1; a2 += q2; a3 += q3;
        a0 += bgv.x; a1 += bgv.y; a2 += bgv.z; a3 += bgv.w;

        // LayerNorm over 128 cols (reduce within the 32-lane half)
        float ssum = (a0 + a1) + (a2 + a3);
        #pragma unroll
        for (int off = 16; off; off >>= 1) ssum += __shfl_xor(ssum, off, 64);
        float mu = ssum * (1.0f / 128.0f);
        float d0 = a0 - mu, d1 = a1 - mu, d2 = a2 - mu, d3 = a3 - mu;
        float vsum = (d0 * d0 + d1 * d1) + (d2 * d2 + d3 * d3);
        #pragma unroll
        for (int off = 16; off; off >>= 1) vsum += __shfl_xor(vsum, off, 64);
        float rstd = rsqrtf(vsum * (1.0f / 128.0f) + LN_EPS);

        float o0 = fmaxf(gv.x * d0 * rstd + bv.x, 0.f);
        float o1 = fmaxf(gv.y * d1 * rstd + bv.y, 0.f);
        float o2 = fmaxf(gv.z * d2 * rstd + bv.z, 0.f);
        float o3 = fmaxf(gv.w * d3 * rstd + bv.w, 0.f);
        uint2 o;
        o.x = (u32)f2bf(o0) | ((u32)f2bf(o1) << 16);
        o.y = (u32)f2bf(o2) | ((u32)f2bf(o3) << 16);
        *(uint2*)&outHi[(size_t)wid * 512 + c0] = o;
    }
}

// ---------------------------------------------------------------------------
// Host launcher
// ---------------------------------------------------------------------------
extern "C" void kernel_launch(void* const* d_in, const int* in_sizes, int n_in,
                              void* d_out, int out_size, void* d_ws, size_t ws_size,
                              hipStream_t stream) {
    const float* x   = (const float*)d_in[0];
    const int*   ei  = (const int*)  d_in[1];
    const float* Wg  = (const float*)d_in[2];
    const float* bg  = (const float*)d_in[3];
    const float* lng = (const float*)d_in[4];
    const float* lnb = (const float*)d_in[5];
    const float* W1  = (const float*)d_in[6];
    const float* b1  = (const float*)d_in[7];
    const float* W2  = (const float*)d_in[8];
    const float* b2  = (const float*)d_in[9];
    float* out = (float*)d_out;

    const int N = in_sizes[0] / D;
    const int E = in_sizes[1] / 2;
    const int* srcp = ei;
    const int* dstp = ei + E;

    char* ws = (char*)d_ws;
    size_t off = 0;
    auto alloc = [&](size_t bytes) -> void* {
        void* p = ws + off;
        off += (bytes + 511) & ~(size_t)511;
        return p;
    };
    int*   cnt    = (int*)  alloc((size_t)N * 4);
    int*   rowptr = (int*)  alloc((size_t)(N + 1) * 4);
    int*   cursor = (int*)  alloc((size_t)N * 4);
    int*   bsum   = (int*)  alloc(64 * 4);
    int2*  ecol   = (int2*) alloc((size_t)E * 8);
    float* dinv   = (float*)alloc((size_t)N * 4);
    u16*   hWb    = (u16*)  alloc((size_t)N * HH * 2);       // layer GEMM bf16 out
    u16*   xcH    = (u16*)  alloc((size_t)N * 512 * 2);      // [x|f1|f2|f3] bf16
    u16*   WgtH   = (u16*)  alloc((size_t)NLAYERS * D * HH * 2);
    u16*   W1tH   = (u16*)  alloc((size_t)(D + NLAYERS * HH) * HH * 2);
    u16*   W2tH   = (u16*)  alloc((size_t)HH * CC * 2);
    u16*   W2tL   = (u16*)  alloc((size_t)HH * CC * 2);

    const int B = 256;
    const int gE = (E + B - 1) / B;
    const int nsb = (N + 1023) / 1024;

    // zero degree counts (stream-ordered; graph-capture legal)
    hipMemsetAsync(cnt, 0, (size_t)N * 4, stream);

    // fused prep: x->bf16 (x4) + all weight tilings + edge counting
    const int prepTotal = N * (D / 4) + NLAYERS * D * HH
                        + (D + NLAYERS * HH) * HH + HH * CC + E;
    k_prep<<<(prepTotal + B - 1) / B, B, 0, stream>>>(x, xcH, Wg, WgtH, W1, W1tH,
                                                      W2, W2tH, W2tL, dstp, cnt, N, E);
    k_scan_a<<<nsb, 1024, 0, stream>>>(cnt, rowptr, bsum, N);
    k_scan_c<<<(N + B - 1) / B, B, 0, stream>>>(rowptr, bsum, cnt, dinv, cursor, N, E, nsb);
    k_scatter<<<gE, B, 0, stream>>>(srcp, dstp, dinv, cursor, ecol, E);

    const int gemmBlocks = (N + 63) / 64;
    const int mlpBlocks  = (N + 63) / 64;
    const int aggBlocks  = 2048;   // persistent: 8192 waves x 2 nodes

    for (int l = 0; l < NLAYERS; ++l) {
        // hWb = bf16(h @ Wg[l])  (bias added after aggregation)
        k_gemm_lf<<<gemmBlocks, B, 0, stream>>>(xcH, l * HH,
                                                WgtH + (size_t)l * D * HH, hWb, N);
        k_agg_ln<<<aggBlocks, B, 0, stream>>>(hWb, rowptr, ecol, dinv,
                                              bg + (size_t)l * HH,
                                              lng + (size_t)l * HH,
                                              lnb + (size_t)l * HH,
                                              xcH + (size_t)(l + 1) * HH, N);
    }

    // out = softmax(relu([x|f1|f2|f3] @ W1 + b1) @ W2 + b2), fused
    k_mlp_fused<<<mlpBlocks, B, 0, stream>>>(xcH, W1tH, b1,
                                             W2tH, W2tL, b2, out, N);
}

// Round 12
// 289.292 us; speedup vs baseline: 1.0961x; 1.0163x over previous
//
#include <hip/hip_runtime.h>
#include <math.h>

// Problem constants (shapes fixed by the reference)
#define D 128
#define HH 128
#define CC 64
#define NLAYERS 3
#define LN_EPS 1e-5f

typedef __attribute__((ext_vector_type(8))) short bf16x8;
typedef __attribute__((ext_vector_type(4))) float f32x4;
typedef unsigned short u16;
typedef unsigned int u32;

// round-to-nearest-even fp32 -> bf16 bits
__device__ __forceinline__ u16 f2bf(float f) {
    u32 u = __float_as_uint(f);
    u32 r = u + 0x7FFFu + ((u >> 16) & 1u);
    return (u16)(r >> 16);
}
__device__ __forceinline__ float bf2f(u16 h) {
    return __uint_as_float(((u32)h) << 16);
}

// async global->LDS DMA, 16 B per lane (dest = wave-uniform base + lane*16)
__device__ __forceinline__ void gload_lds16(const void* g, void* l) {
    __builtin_amdgcn_global_load_lds(
        (const __attribute__((address_space(1))) void*)g,
        (__attribute__((address_space(3))) void*)l, 16, 0, 0);
}

// ---------------------------------------------------------------------------
// k_prep: fused setup — x->bf16 (float4) + tile Wg/W1/W2 + edge counting
// (cnt zeroed by hipMemsetAsync before this launch).
// Tiled layout: [kc][q][n][j], k = kc*32 + q*8 + j.
// ---------------------------------------------------------------------------
__global__ void k_prep(const float* __restrict__ x, u16* __restrict__ xh,
                       const float* __restrict__ Wg, u16* __restrict__ WgtH,
                       const float* __restrict__ W1, u16* __restrict__ W1tH,
                       const float* __restrict__ W2, u16* __restrict__ W2tH,
                       u16* __restrict__ W2tL,
                       const int* __restrict__ dst, int* __restrict__ cnt,
                       int N, int E)
{
    int i = blockIdx.x * blockDim.x + threadIdx.x;
    // seg 0: x -> bf16 hi, 4 elements per thread (float4 load, ushort4 store)
    int nx4 = N * (D / 4);
    if (i < nx4) {
        float4 v = *(const float4*)(x + (size_t)i * 4);
        int row = i >> 5, c = (i & 31) << 2;
        ushort4 o;
        o.x = f2bf(v.x); o.y = f2bf(v.y); o.z = f2bf(v.z); o.w = f2bf(v.w);
        *(ushort4*)&xh[(size_t)row * 512 + c] = o;
        return;
    }
    i -= nx4;
    // seg 1: Wg (3 stacked 128x128 matrices; layout linear in kc)
    if (i < NLAYERS * D * HH) {
        int k = i >> 7, n = i & 127;
        int kc = k >> 5, q = (k >> 3) & 3, j = k & 7;
        WgtH[(((kc * 4 + q) << 7) + n) * 8 + j] = f2bf(Wg[i]);
        return;
    }
    i -= NLAYERS * D * HH;
    // seg 2: W1 (512x128)
    if (i < (D + NLAYERS * HH) * HH) {
        int k = i >> 7, n = i & 127;
        int kc = k >> 5, q = (k >> 3) & 3, j = k & 7;
        W1tH[(((kc * 4 + q) << 7) + n) * 8 + j] = f2bf(W1[i]);
        return;
    }
    i -= (D + NLAYERS * HH) * HH;
    // seg 3: W2 (128x64), hi + lo (split-3 in mlp phase 2)
    if (i < HH * CC) {
        int k = i >> 6, n = i & 63;
        int kc = k >> 5, q = (k >> 3) & 3, j = k & 7;
        float v = W2[i];
        u16 h = f2bf(v);
        int o = (((kc * 4 + q) << 6) + n) * 8 + j;
        W2tH[o] = h;
        W2tL[o] = f2bf(v - bf2f(h));
        return;
    }
    i -= HH * CC;
    // seg 4: edge degree count (cnt pre-zeroed by hipMemsetAsync)
    if (i < E) atomicAdd(&cnt[dst[i]], 1);
}

// ---------------------------------------------------------------------------
// CSR build: scan_a -> scan_c -> scatter. Separate small launches:
// grid.sync() on MI355X costs ~100 µs/barrier (round-2: fused coop = 527 µs).
// ---------------------------------------------------------------------------

// shuffle-based block scan: 2 barriers
__global__ void k_scan_a(const int* __restrict__ cnt, int* __restrict__ rowptr,
                         int* __restrict__ bsum, int N) {
    __shared__ int ws[16];
    int tid  = threadIdx.x;              // 1024
    int lane = tid & 63, wv = tid >> 6;  // 16 waves
    int i = blockIdx.x * 1024 + tid;
    int v = (i < N) ? cnt[i] : 0;
    int incl = v;
    #pragma unroll
    for (int off = 1; off < 64; off <<= 1) {
        int u = __shfl_up(incl, off, 64);
        if (lane >= off) incl += u;
    }
    if (lane == 63) ws[wv] = incl;
    __syncthreads();
    if (wv == 0) {
        int s = (lane < 16) ? ws[lane] : 0;
        #pragma unroll
        for (int off = 1; off < 16; off <<= 1) {
            int u = __shfl_up(s, off, 64);
            if (lane >= off) s += u;
        }
        if (lane < 16) ws[lane] = s;    // inclusive over wave sums
    }
    __syncthreads();
    int add = (wv == 0) ? 0 : ws[wv - 1];
    if (i < N) rowptr[i] = add + incl - v;
    if (tid == 1023) bsum[blockIdx.x] = ws[15];
}

// finalize: re-scan <=64 block sums (first wave), apply; compute dinv.
__global__ void k_scan_c(int* __restrict__ rowptr, const int* __restrict__ bsum,
                         const int* __restrict__ cnt, float* __restrict__ dinv,
                         int* __restrict__ cursor, int N, int E, int nsb) {
    __shared__ int sb[64];
    if (threadIdx.x < 64) {
        int t = threadIdx.x;
        int v = (t < nsb) ? bsum[t] : 0;
        int incl = v;
        #pragma unroll
        for (int off = 1; off < 64; off <<= 1) {
            int u = __shfl_up(incl, off, 64);
            if (t >= off) incl += u;
        }
        sb[t] = incl - v;   // exclusive
    }
    __syncthreads();
    int i = blockIdx.x * blockDim.x + threadIdx.x;
    if (i < N) {
        int v = rowptr[i] + sb[i >> 10];
        rowptr[i] = v;
        cursor[i] = v;
        dinv[i] = rsqrtf(1.0f + (float)cnt[i]);
    }
    if (i == 0) rowptr[N] = E;
}

// Scatter edges into CSR; pack src index + precomputed coef (dinv_s * dinv_d)
__global__ void k_scatter(const int* __restrict__ src, const int* __restrict__ dst,
                          const float* __restrict__ dinv,
                          int* __restrict__ cursor, int2* __restrict__ ecol, int E) {
    int i = blockIdx.x * blockDim.x + threadIdx.x;
    if (i < E) {
        int s = src[i], d = dst[i];
        int p = atomicAdd(&cursor[d], 1);
        float c = dinv[s] * dinv[d];
        ecol[p] = make_int2(s, __float_as_int(c));
    }
}

// ---------------------------------------------------------------------------
// Layer GEMM v3 — 2-tile ping-pong: block owns 128 rows as two 64-row tiles;
// tile 1 stages (global_load_lds DMA) while tile 0 computes. One cold stall
// per 2 tiles. B fragments loaded once (shared by both tiles). XOR-granule
// swizzle on the GLOBAL source (LDS dest linear) + same XOR on ds_read.
// ---------------------------------------------------------------------------
__global__ __launch_bounds__(256) void k_gemm_lf(
    const u16* __restrict__ A, int colOff,
    const u16* __restrict__ Bt, u16* __restrict__ OUTb, int N)
{
    __shared__ u16 sA[2][64 * 128];   // 32 KB ping-pong

    const int tid  = threadIdx.x;
    const int lane = tid & 63;
    const int wave = tid >> 6;
    const int wr   = wave & 1;
    const int wc   = wave >> 1;
    const int quad = lane >> 4;
    const int l15  = lane & 15;
    const int row0 = blockIdx.x * 128;

    // stage helper rounds: 4 x 256 lanes x 16 B = 16 KB per tile
    #define STAGE_A(buf, base)                                                  \
        {                                                                       \
            _Pragma("unroll")                                                   \
            for (int rd = 0; rd < 4; ++rd) {                                    \
                int idx  = rd * 256 + tid;                                      \
                int row  = idx >> 4;                                            \
                int gp   = idx & 15;                                            \
                int gs   = gp ^ (row & 7);                                      \
                int grow = (base) + row; if (grow >= N) grow = N - 1;           \
                const u16* srcp_ = A + (size_t)grow * 512 + colOff + gs * 8;    \
                gload_lds16(srcp_, &sA[buf][(size_t)(rd * 256 + (tid & ~63)) * 8]); \
            }                                                                   \
        }

    STAGE_A(0, row0)

    const u16* pB = Bt + ((size_t)quad * 128 + wc * 64 + l15) * 8;
    bf16x8 bh[4][4];
    #pragma unroll
    for (int kc = 0; kc < 4; ++kc)
        #pragma unroll
        for (int j = 0; j < 4; ++j)
            bh[kc][j] = *(const bf16x8*)(pB + (size_t)kc * 4096 + j * 128);

    const int rL[2] = { wr * 32 + l15, wr * 32 + 16 + l15 };

    #pragma unroll
    for (int t = 0; t < 2; ++t) {
        __syncthreads();                       // sA[t] ready (drains DMA)
        if (t == 0) STAGE_A(1, row0 + 64)      // overlap with tile-0 compute

        bf16x8 ah[4][2];
        #pragma unroll
        for (int kc = 0; kc < 4; ++kc)
            #pragma unroll
            for (int i = 0; i < 2; ++i)
                ah[kc][i] = *(const bf16x8*)&sA[t][rL[i] * 128
                               + (((kc << 2) | quad) ^ (rL[i] & 7)) * 8];

        f32x4 acc[2][4];
        #pragma unroll
        for (int i = 0; i < 2; ++i)
            #pragma unroll
            for (int j = 0; j < 4; ++j)
                #pragma unroll
                for (int r = 0; r < 4; ++r) acc[i][j][r] = 0.f;

        #pragma unroll
        for (int kc = 0; kc < 4; ++kc)
            #pragma unroll
            for (int i = 0; i < 2; ++i)
                #pragma unroll
                for (int j = 0; j < 4; ++j)
                    acc[i][j] = __builtin_amdgcn_mfma_f32_16x16x32_bf16(
                        ah[kc][i], bh[kc][j], acc[i][j], 0, 0, 0);

        #pragma unroll
        for (int i = 0; i < 2; ++i)
            #pragma unroll
            for (int j = 0; j < 4; ++j) {
                int col = wc * 64 + j * 16 + l15;
                #pragma unroll
                for (int r = 0; r < 4; ++r) {
                    int grow = row0 + t * 64 + wr * 32 + i * 16 + quad * 4 + r;
                    if (grow < N)
                        OUTb[(size_t)grow * 128 + col] = f2bf(acc[i][j][r]);
                }
            }
    }
    #undef STAGE_A
}

// ---------------------------------------------------------------------------
// Fused MLP v7 — ping-pong staged A + LDS aliasing. Phase 1: smem[2] is the
// sA double buffer (stage kp+1 issued right after the barrier that readies
// kp -> DMA hides under 32 MFMAs + B loads); ONE barrier per pass instead of
// two, ONE cold stall instead of four. After phase 1 the same 32 KB is
// reused for sZh/sZl (barrier-separated). LDS 48 -> 32 KB.
// 64 rows x 128 cols, 4 waves (32x64 tile); phase 2 on all 4 waves.
// ---------------------------------------------------------------------------
__global__ __launch_bounds__(256) void k_mlp_fused(
    const u16* __restrict__ xcH,
    const u16* __restrict__ B1t, const float* __restrict__ b1,
    const u16* __restrict__ W2h, const u16* __restrict__ W2l,
    const float* __restrict__ b2, float* __restrict__ out, int N)
{
    __shared__ u16 smem[2][64 * 128];  // phase 1: sA ping-pong; phase 2: sZh/sZl

    const int tid  = threadIdx.x;
    const int lane = tid & 63;
    const int wave = tid >> 6;
    const int wr   = wave & 1;   // row half (32 rows)
    const int wc   = wave >> 1;  // col half (64 cols)
    const int quad = lane >> 4;
    const int l15  = lane & 15;
    const int row0 = blockIdx.x * 64;

    #define STAGE_K(buf, kp)                                                    \
        {                                                                       \
            _Pragma("unroll")                                                   \
            for (int rd = 0; rd < 4; ++rd) {                                    \
                int idx  = rd * 256 + tid;                                      \
                int row  = idx >> 4;                                            \
                int gp   = idx & 15;                                            \
                int gs   = gp ^ (row & 7);                                      \
                int grow = row0 + row; if (grow >= N) grow = N - 1;             \
                const u16* srcp_ = xcH + (size_t)grow * 512 + (kp) * 128 + gs * 8; \
                gload_lds16(srcp_, &smem[buf][(size_t)(rd * 256 + (tid & ~63)) * 8]); \
            }                                                                   \
        }

    const u16* pB = B1t + ((size_t)quad * 128 + wc * 64 + l15) * 8;
    const int rL[2] = { wr * 32 + l15, wr * 32 + 16 + l15 };

    f32x4 acc[2][4];
    #pragma unroll
    for (int i = 0; i < 2; ++i)
        #pragma unroll
        for (int j = 0; j < 4; ++j)
            #pragma unroll
            for (int r = 0; r < 4; ++r) acc[i][j][r] = 0.f;

    STAGE_K(0, 0)

    #pragma unroll
    for (int kp = 0; kp < 4; ++kp) {
        __syncthreads();                           // smem[kp&1] ready
        if (kp < 3) STAGE_K((kp + 1) & 1, kp + 1)  // overlap with compute

        bf16x8 bh[4][4];
        #pragma unroll
        for (int c = 0; c < 4; ++c)
            #pragma unroll
            for (int j = 0; j < 4; ++j)
                bh[c][j] = *(const bf16x8*)(pB + (size_t)(kp * 4 + c) * 4096 + j * 128);

        bf16x8 ah[4][2];
        #pragma unroll
        for (int c = 0; c < 4; ++c)
            #pragma unroll
            for (int i = 0; i < 2; ++i)
                ah[c][i] = *(const bf16x8*)&smem[kp & 1][rL[i] * 128
                               + (((c << 2) | quad) ^ (rL[i] & 7)) * 8];

        #pragma unroll
        for (int c = 0; c < 4; ++c)
            #pragma unroll
            for (int i = 0; i < 2; ++i)
                #pragma unroll
                for (int j = 0; j < 4; ++j)
                    acc[i][j] = __builtin_amdgcn_mfma_f32_16x16x32_bf16(
                        ah[c][i], bh[c][j], acc[i][j], 0, 0, 0);
    }
    #undef STAGE_K

    __syncthreads();   // all sA reads done -> safe to reuse smem for sZ
    u16* sZh = smem[0];
    u16* sZl = smem[1];

    // bias + relu + hi/lo split -> LDS (each wave writes its 32x64 tile)
    #pragma unroll
    for (int jt = 0; jt < 4; ++jt) {
        int col = wc * 64 + jt * 16 + l15;
        float bv = b1[col];
        int qq = col >> 3, jj = col & 7;
        #pragma unroll
        for (int i = 0; i < 2; ++i) {
            #pragma unroll
            for (int rr = 0; rr < 4; ++rr) {
                int row = wr * 32 + i * 16 + quad * 4 + rr;
                float v = fmaxf(acc[i][jt][rr] + bv, 0.f);
                u16 h = f2bf(v);
                sZh[(qq * 64 + row) * 8 + jj] = h;
                sZl[(qq * 64 + row) * 8 + jj] = f2bf(v - bf2f(h));
            }
        }
    }
    __syncthreads();

    // phase 2: MLP2 (128->64) + softmax; ALL 4 waves, 16 rows each
    {
        f32x4 oacc[4];
        #pragma unroll
        for (int j = 0; j < 4; ++j)
            #pragma unroll
            for (int r = 0; r < 4; ++r) oacc[j][r] = 0.f;

        #pragma unroll
        for (int kc = 0; kc < 4; ++kc) {
            int qq = kc * 4 + quad;
            bf16x8 zh = *(const bf16x8*)&sZh[(qq * 64 + wave * 16 + l15) * 8];
            bf16x8 zl = *(const bf16x8*)&sZl[(qq * 64 + wave * 16 + l15) * 8];
            #pragma unroll
            for (int jt = 0; jt < 4; ++jt) {
                int n = jt * 16 + l15;
                bf16x8 wh = *(const bf16x8*)&W2h[(qq * 64 + n) * 8];
                bf16x8 wl = *(const bf16x8*)&W2l[(qq * 64 + n) * 8];
                oacc[jt] = __builtin_amdgcn_mfma_f32_16x16x32_bf16(zh, wh, oacc[jt], 0, 0, 0);
                oacc[jt] = __builtin_amdgcn_mfma_f32_16x16x32_bf16(zh, wl, oacc[jt], 0, 0, 0);
                oacc[jt] = __builtin_amdgcn_mfma_f32_16x16x32_bf16(zl, wh, oacc[jt], 0, 0, 0);
            }
        }

        #pragma unroll
        for (int jt = 0; jt < 4; ++jt) {
            float bv = b2[jt * 16 + l15];
            #pragma unroll
            for (int r = 0; r < 4; ++r) oacc[jt][r] += bv;
        }
        #pragma unroll
        for (int r = 0; r < 4; ++r) {
            float m = fmaxf(fmaxf(oacc[0][r], oacc[1][r]), fmaxf(oacc[2][r], oacc[3][r]));
            #pragma unroll
            for (int mask = 8; mask; mask >>= 1) m = fmaxf(m, __shfl_xor(m, mask, 64));
            float p0 = __expf(oacc[0][r] - m);
            float p1 = __expf(oacc[1][r] - m);
            float p2 = __expf(oacc[2][r] - m);
            float p3 = __expf(oacc[3][r] - m);
            float s = p0 + p1 + p2 + p3;
            #pragma unroll
            for (int mask = 8; mask; mask >>= 1) s += __shfl_xor(s, mask, 64);
            float inv = 1.0f / s;
            int grow = row0 + wave * 16 + quad * 4 + r;
            if (grow < N) {
                float* o = out + (size_t)grow * CC + l15;
                o[0]  = p0 * inv;
                o[16] = p1 * inv;
                o[32] = p2 * inv;
                o[48] = p3 * inv;
            }
        }
    }
}

// ---------------------------------------------------------------------------
// Aggregation (symmetric-normalized, self-loop) + bias + LayerNorm + ReLU.
// Node-per-half-wave (verified round 6). 4 cols/lane, 8B gathers, batch-4,
// 2 nodes/wave. ~5 TB/s effective — unchanged.
// ---------------------------------------------------------------------------
__global__ __launch_bounds__(256, 8) void k_agg_ln(
    const u16* __restrict__ hWb,
    const int* __restrict__ rowptr, const int2* __restrict__ ecol,
    const float* __restrict__ dinv,
    const float* __restrict__ bg, const float* __restrict__ g,
    const float* __restrict__ b,
    u16* __restrict__ outHi, int N)
{
    const int lane = threadIdx.x & 63;
    const int c0   = (lane & 31) << 2;  // 4 owned columns (within half)

    const float4 bgv = *(const float4*)(bg + c0);
    const float4 gv  = *(const float4*)(g + c0);
    const float4 bv  = *(const float4*)(b + c0);

    const int nslots = gridDim.x * 8;   // 2 nodes per wave, 4 waves per block
    for (int wid = blockIdx.x * 8 + ((threadIdx.x >> 6) << 1) + (lane >> 5);
         wid < N; wid += nslots) {
        float di = dinv[wid];
        float sc = di * di;

        // self-loop term
        uint2 hv = *(const uint2*)(hWb + (size_t)wid * HH + c0);
        float a0 = bf2f((u16)hv.x) * sc;
        float a1 = bf2f((u16)(hv.x >> 16)) * sc;
        float a2 = bf2f((u16)hv.y) * sc;
        float a3 = bf2f((u16)(hv.y >> 16)) * sc;
        float q0 = 0.f, q1 = 0.f, q2 = 0.f, q3 = 0.f;

        int e0 = rowptr[wid];
        int m  = rowptr[wid + 1] - e0;
        const int2* ep = ecol + e0;

        int k = 0;
        for (; k + 4 <= m; k += 4) {     // 4 independent gathers in flight
            int2 p[4];
            uint2 v[4];
            #pragma unroll
            for (int t = 0; t < 4; ++t) p[t] = ep[k + t];
            #pragma unroll
            for (int t = 0; t < 4; ++t)
                v[t] = *(const uint2*)(hWb + (size_t)p[t].x * HH + c0);
            #pragma unroll
            for (int t = 0; t < 4; ++t) {
                float c = __int_as_float(p[t].y);
                float x0 = bf2f((u16)v[t].x) * c;
                float x1 = bf2f((u16)(v[t].x >> 16)) * c;
                float x2 = bf2f((u16)v[t].y) * c;
                float x3 = bf2f((u16)(v[t].y >> 16)) * c;
                if (t & 1) { q0 += x0; q1 += x1; q2 += x2; q3 += x3; }
                else       { a0 += x0; a1 += x1; a2 += x2; a3 += x3; }
            }
        }
        if (k < m) {                     // tail <=3, issue together
            int2 p0 = ep[k];
            int2 p1 = (k + 1 < m) ? ep[k + 1] : p0;
            int2 p2 = (k + 2 < m) ? ep[k + 2] : p0;
            uint2 v0 = *(const uint2*)(hWb + (size_t)p0.x * HH + c0);
            uint2 v1 = *(const uint2*)(hWb + (size_t)p1.x * HH + c0);
            uint2 v2 = *(const uint2*)(hWb + (size_t)p2.x * HH + c0);
            float cc0 = __int_as_float(p0.y);
            float cc1 = (k + 1 < m) ? __int_as_float(p1.y) : 0.f;
            float cc2 = (k + 2 < m) ? __int_as_float(p2.y) : 0.f;
            a0 += bf2f((u16)v0.x) * cc0;  a1 += bf2f((u16)(v0.x >> 16)) * cc0;
            a2 += bf2f((u16)v0.y) * cc0;  a3 += bf2f((u16)(v0.y >> 16)) * cc0;
            q0 += bf2f((u16)v1.x) * cc1;  q1 += bf2f((u16)(v1.x >> 16)) * cc1;
            q2 += bf2f((u16)v1.y) * cc1;  q3 += bf2f((u16)(v1.y >> 16)) * cc1;
            a0 += bf2f((u16)v2.x) * cc2;  a1 += bf2f((u16)(v2.x >> 16)) * cc2;
            a2 += bf2f((u16)v2.y) * cc2;  a3 += bf2f((u16)(v2.y >> 16)) * cc2;
        }
        a0 += q0; a1 += q1; a2 += q2; a3 += q3;
        a0 += bgv.x; a1 += bgv.y; a2 += bgv.z; a3 += bgv.w;

        // LayerNorm over 128 cols (reduce within the 32-lane half)
        float ssum = (a0 + a1) + (a2 + a3);
        #pragma unroll
        for (int off = 16; off; off >>= 1) ssum += __shfl_xor(ssum, off, 64);
        float mu = ssum * (1.0f / 128.0f);
        float d0 = a0 - mu, d1 = a1 - mu, d2 = a2 - mu, d3 = a3 - mu;
        float vsum = (d0 * d0 + d1 * d1) + (d2 * d2 + d3 * d3);
        #pragma unroll
        for (int off = 16; off; off >>= 1) vsum += __shfl_xor(vsum, off, 64);
        float rstd = rsqrtf(vsum * (1.0f / 128.0f) + LN_EPS);

        float o0 = fmaxf(gv.x * d0 * rstd + bv.x, 0.f);
        float o1 = fmaxf(gv.y * d1 * rstd + bv.y, 0.f);
        float o2 = fmaxf(gv.z * d2 * rstd + bv.z, 0.f);
        float o3 = fmaxf(gv.w * d3 * rstd + bv.w, 0.f);
        uint2 o;
        o.x = (u32)f2bf(o0) | ((u32)f2bf(o1) << 16);
        o.y = (u32)f2bf(o2) | ((u32)f2bf(o3) << 16);
        *(uint2*)&outHi[(size_t)wid * 512 + c0] = o;
    }
}

// ---------------------------------------------------------------------------
// Host launcher
// ---------------------------------------------------------------------------
extern "C" void kernel_launch(void* const* d_in, const int* in_sizes, int n_in,
                              void* d_out, int out_size, void* d_ws, size_t ws_size,
                              hipStream_t stream) {
    const float* x   = (const float*)d_in[0];
    const int*   ei  = (const int*)  d_in[1];
    const float* Wg  = (const float*)d_in[2];
    const float* bg  = (const float*)d_in[3];
    const float* lng = (const float*)d_in[4];
    const float* lnb = (const float*)d_in[5];
    const float* W1  = (const float*)d_in[6];
    const float* b1  = (const float*)d_in[7];
    const float* W2  = (const float*)d_in[8];
    const float* b2  = (const float*)d_in[9];
    float* out = (float*)d_out;

    const int N = in_sizes[0] / D;
    const int E = in_sizes[1] / 2;
    const int* srcp = ei;
    const int* dstp = ei + E;

    char* ws = (char*)d_ws;
    size_t off = 0;
    auto alloc = [&](size_t bytes) -> void* {
        void* p = ws + off;
        off += (bytes + 511) & ~(size_t)511;
        return p;
    };
    int*   cnt    = (int*)  alloc((size_t)N * 4);
    int*   rowptr = (int*)  alloc((size_t)(N + 1) * 4);
    int*   cursor = (int*)  alloc((size_t)N * 4);
    int*   bsum   = (int*)  alloc(64 * 4);
    int2*  ecol   = (int2*) alloc((size_t)E * 8);
    float* dinv   = (float*)alloc((size_t)N * 4);
    u16*   hWb    = (u16*)  alloc((size_t)N * HH * 2);       // layer GEMM bf16 out
    u16*   xcH    = (u16*)  alloc((size_t)N * 512 * 2);      // [x|f1|f2|f3] bf16
    u16*   WgtH   = (u16*)  alloc((size_t)NLAYERS * D * HH * 2);
    u16*   W1tH   = (u16*)  alloc((size_t)(D + NLAYERS * HH) * HH * 2);
    u16*   W2tH   = (u16*)  alloc((size_t)HH * CC * 2);
    u16*   W2tL   = (u16*)  alloc((size_t)HH * CC * 2);

    const int B = 256;
    const int gE = (E + B - 1) / B;
    const int nsb = (N + 1023) / 1024;

    // zero degree counts (stream-ordered; graph-capture legal)
    hipMemsetAsync(cnt, 0, (size_t)N * 4, stream);

    // fused prep: x->bf16 (x4) + all weight tilings + edge counting
    const int prepTotal = N * (D / 4) + NLAYERS * D * HH
                        + (D + NLAYERS * HH) * HH + HH * CC + E;
    k_prep<<<(prepTotal + B - 1) / B, B, 0, stream>>>(x, xcH, Wg, WgtH, W1, W1tH,
                                                      W2, W2tH, W2tL, dstp, cnt, N, E);
    k_scan_a<<<nsb, 1024, 0, stream>>>(cnt, rowptr, bsum, N);
    k_scan_c<<<(N + B - 1) / B, B, 0, stream>>>(rowptr, bsum, cnt, dinv, cursor, N, E, nsb);
    k_scatter<<<gE, B, 0, stream>>>(srcp, dstp, dinv, cursor, ecol, E);

    const int gemmBlocks = (N + 127) / 128;   // 2-tile blocks
    const int mlpBlocks  = (N + 63) / 64;
    const int aggBlocks  = 2048;              // persistent: 8192 waves x 2 nodes

    for (int l = 0; l < NLAYERS; ++l) {
        // hWb = bf16(h @ Wg[l])  (bias added after aggregation)
        k_gemm_lf<<<gemmBlocks, B, 0, stream>>>(xcH, l * HH,
                                                WgtH + (size_t)l * D * HH, hWb, N);
        k_agg_ln<<<aggBlocks, B, 0, stream>>>(hWb, rowptr, ecol, dinv,
                                              bg + (size_t)l * HH,
                                              lng + (size_t)l * HH,
                                              lnb + (size_t)l * HH,
                                              xcH + (size_t)(l + 1) * HH, N);
    }

    // out = softmax(relu([x|f1|f2|f3] @ W1 + b1) @ W2 + b2), fused
    k_mlp_fused<<<mlpBlocks, B, 0, stream>>>(xcH, W1tH, b1,
                                             W2tH, W2tL, b2, out, N);
}